// Round 1
// baseline (2168.874 us; speedup 1.0000x reference)
//
#include <hip/hip_runtime.h>
#include <cmath>
#include <cstdint>

typedef __bf16 bf16_t;
typedef __bf16 bf16x8 __attribute__((ext_vector_type(8)));
typedef __bf16 bf16x4 __attribute__((ext_vector_type(4)));
typedef float  f32x4  __attribute__((ext_vector_type(4)));
typedef unsigned short ushort8 __attribute__((ext_vector_type(8)));

#define DEPTH 6
#define DIM   768
#define HEADS 12
#define DH    64
#define MLPD  3072
#define SEQ   1024
#define BATCH 4
#define MTOT  (BATCH*SEQ)   /* 4096 rows */
#define QKVN  2304          /* 3*768 */

static __device__ __forceinline__ bf16x8 ld8(const bf16_t* p) {
    return *(const bf16x8*)p;
}

// ---------------- fp32 -> bf16 weight conversion ----------------
__global__ __launch_bounds__(256) void cvt4_kernel(const float4* __restrict__ in,
                                                   bf16_t* __restrict__ out, int n4) {
    int i = blockIdx.x * 256 + threadIdx.x;
    if (i >= n4) return;
    float4 v = in[i];
    bf16x4 o;
    o[0] = (bf16_t)v.x; o[1] = (bf16_t)v.y; o[2] = (bf16_t)v.z; o[3] = (bf16_t)v.w;
    *(bf16x4*)(out + 4 * (size_t)i) = o;
}

// ---------------- LayerNorm: fp32 x -> bf16 h ----------------
__global__ __launch_bounds__(256) void ln_kernel(const float* __restrict__ x,
                                                 const float* __restrict__ w,
                                                 const float* __restrict__ b,
                                                 bf16_t* __restrict__ h) {
    int row = blockIdx.x, t = threadIdx.x;
    const float* xr = x + (size_t)row * DIM;
    float v0 = xr[t], v1 = xr[t + 256], v2 = xr[t + 512];
    float s = v0 + v1 + v2;
    float q = v0 * v0 + v1 * v1 + v2 * v2;
    #pragma unroll
    for (int off = 32; off > 0; off >>= 1) {
        s += __shfl_down(s, off);
        q += __shfl_down(q, off);
    }
    __shared__ float ss[4], sq[4], stat[2];
    if ((t & 63) == 0) { ss[t >> 6] = s; sq[t >> 6] = q; }
    __syncthreads();
    if (t == 0) {
        float S = ss[0] + ss[1] + ss[2] + ss[3];
        float Q = sq[0] + sq[1] + sq[2] + sq[3];
        float mean = S * (1.0f / DIM);
        float var  = Q * (1.0f / DIM) - mean * mean;
        stat[0] = mean;
        stat[1] = rsqrtf(var + 1e-5f);
    }
    __syncthreads();
    float mean = stat[0], rstd = stat[1];
    bf16_t* hr = h + (size_t)row * DIM;
    hr[t]       = (bf16_t)((v0 - mean) * rstd * w[t]       + b[t]);
    hr[t + 256] = (bf16_t)((v1 - mean) * rstd * w[t + 256] + b[t + 256]);
    hr[t + 512] = (bf16_t)((v2 - mean) * rstd * w[t + 512] + b[t + 512]);
}

// ---------------- bf16 MFMA GEMM, 128x128 tile, BK=32 ----------------
// EPI 0: Cb = A@B (bf16)      [QKV]
// EPI 1: Cb = gelu(A@B+bias)  [MLP1]
// EPI 2: Cf += A@B + bias     [proj / MLP2 residual, fp32 in-place]
template <int EPI>
__global__ __launch_bounds__(256) void gemm_kernel(const bf16_t* __restrict__ A,
                                                   const bf16_t* __restrict__ B,
                                                   const float* __restrict__ bias,
                                                   bf16_t* __restrict__ Cb,
                                                   float* __restrict__ Cf,
                                                   int N, int K) {
    __shared__ __align__(16) bf16_t As[128 * 40];  // [row][k] stride 40
    __shared__ __align__(16) bf16_t Bs[128 * 40];  // [col][k] stride 40 (transposed)
    int t = threadIdx.x;
    int m0 = blockIdx.y * 128, n0 = blockIdx.x * 128;
    int lane = t & 63, l16 = lane & 15, quad = lane >> 4;
    int wv = t >> 6, wm = wv >> 1, wn = wv & 1;
    f32x4 acc[4][4] = {};
    // staging assignment
    int ar = t >> 2, ak = (t & 3) * 8;      // A: row, k-chunk
    int bp = t & 15, bc = t >> 4;           // B: k-pair, col-chunk
    const bf16_t* Aptr = A + (size_t)(m0 + ar) * K + ak;
    const bf16_t* Bptr = B + (size_t)(2 * bp) * N + n0 + bc * 8;

    for (int k0 = 0; k0 < K; k0 += 32) {
        bf16x8 a0 = ld8(Aptr + k0);
        bf16x8 a1 = ld8(Aptr + (size_t)64 * K + k0);
        bf16x8 b0 = ld8(Bptr + (size_t)k0 * N);
        bf16x8 b1 = ld8(Bptr + (size_t)(k0 + 1) * N);
        __syncthreads();
        *(bf16x8*)&As[ar * 40 + ak]        = a0;
        *(bf16x8*)&As[(ar + 64) * 40 + ak] = a1;
        ushort8 u0 = __builtin_bit_cast(ushort8, b0);
        ushort8 u1 = __builtin_bit_cast(ushort8, b1);
        #pragma unroll
        for (int j = 0; j < 8; j++) {
            unsigned int pr = (unsigned int)u0[j] | ((unsigned int)u1[j] << 16);
            *(unsigned int*)&Bs[(bc * 8 + j) * 40 + 2 * bp] = pr;
        }
        __syncthreads();
        bf16x8 af[4], bfr[4];
        #pragma unroll
        for (int i = 0; i < 4; i++)
            af[i] = ld8(&As[(wm * 64 + i * 16 + l16) * 40 + quad * 8]);
        #pragma unroll
        for (int j = 0; j < 4; j++)
            bfr[j] = ld8(&Bs[(wn * 64 + j * 16 + l16) * 40 + quad * 8]);
        #pragma unroll
        for (int i = 0; i < 4; i++)
            #pragma unroll
            for (int j = 0; j < 4; j++)
                acc[i][j] = __builtin_amdgcn_mfma_f32_16x16x32_bf16(af[i], bfr[j], acc[i][j], 0, 0, 0);
    }

    #pragma unroll
    for (int i = 0; i < 4; i++) {
        int grow = m0 + wm * 64 + i * 16 + quad * 4;
        #pragma unroll
        for (int j = 0; j < 4; j++) {
            int gcol = n0 + wn * 64 + j * 16 + l16;
            float bv = 0.0f;
            if constexpr (EPI != 0) bv = bias[gcol];
            #pragma unroll
            for (int r = 0; r < 4; r++) {
                size_t idx = (size_t)(grow + r) * N + gcol;
                float v = acc[i][j][r];
                if constexpr (EPI == 0) {
                    Cb[idx] = (bf16_t)v;
                } else if constexpr (EPI == 1) {
                    v += bv;
                    v = 0.5f * v * (1.0f + erff(v * 0.70710678118654752f));
                    Cb[idx] = (bf16_t)v;
                } else {
                    Cf[idx] += v + bv;
                }
            }
        }
    }
}

// ---------------- V transpose: qkv V-slice -> Vt[b][h][d][n] ----------------
__global__ __launch_bounds__(256) void vtrans_kernel(const bf16_t* __restrict__ qkv,
                                                     bf16_t* __restrict__ vt) {
    int nt = blockIdx.x;           // 16 tiles of 64 keys
    int bh = blockIdx.y;           // b*HEADS + h
    int b = bh / HEADS, h = bh % HEADS;
    __shared__ bf16_t ts[64 * 65];
    int t = threadIdx.x;
    #pragma unroll
    for (int s = 0; s < 16; s++) {
        int flat = s * 256 + t;
        int r = flat >> 6, d = flat & 63;
        ts[d * 65 + r] = qkv[((size_t)(b * SEQ) + nt * 64 + r) * QKVN + 1536 + h * 64 + d];
    }
    __syncthreads();
    #pragma unroll
    for (int s = 0; s < 16; s++) {
        int flat = s * 256 + t;
        int d = flat >> 6, c = flat & 63;
        vt[((size_t)bh * 64 + d) * SEQ + nt * 64 + c] = ts[d * 65 + c];
    }
}

// ---------------- flash attention: 1 wave per (b,h,16-query tile) ----------------
__global__ __launch_bounds__(64) void attn_kernel(const bf16_t* __restrict__ qkv,
                                                  const bf16_t* __restrict__ vt,
                                                  bf16_t* __restrict__ out) {
    int qt = blockIdx.x, h = blockIdx.y, b = blockIdx.z;
    int lane = threadIdx.x, l16 = lane & 15, quad = lane >> 4;
    int q0 = qt * 16;
    const bf16_t* qbase = qkv + ((size_t)(b * SEQ) + q0 + l16) * QKVN + h * 64;
    bf16x8 qf0 = ld8(qbase + quad * 8);
    bf16x8 qf1 = ld8(qbase + 32 + quad * 8);
    float m[4], l[4];
    f32x4 o[4] = {};
    #pragma unroll
    for (int r = 0; r < 4; r++) { m[r] = -1e30f; l[r] = 0.0f; }
    __shared__ __align__(16) bf16_t plds[16 * 40];
    const bf16_t* kbase = qkv + ((size_t)(b * SEQ) + l16) * QKVN + 768 + h * 64;
    const bf16_t* vbase = vt + ((size_t)(b * HEADS + h) * 64) * SEQ;

    for (int kb = 0; kb < SEQ; kb += 32) {
        f32x4 s[2];
        #pragma unroll
        for (int tt = 0; tt < 2; tt++) {
            const bf16_t* kp = kbase + (size_t)(kb + tt * 16) * QKVN;
            f32x4 z = {};
            z = __builtin_amdgcn_mfma_f32_16x16x32_bf16(qf0, ld8(kp + quad * 8), z, 0, 0, 0);
            z = __builtin_amdgcn_mfma_f32_16x16x32_bf16(qf1, ld8(kp + 32 + quad * 8), z, 0, 0, 0);
            s[tt] = z;
        }
        float p[2][4];
        #pragma unroll
        for (int r = 0; r < 4; r++) {
            float s0 = s[0][r] * 0.125f, s1 = s[1][r] * 0.125f;
            float rm = fmaxf(s0, s1);
            rm = fmaxf(rm, __shfl_xor(rm, 1));
            rm = fmaxf(rm, __shfl_xor(rm, 2));
            rm = fmaxf(rm, __shfl_xor(rm, 4));
            rm = fmaxf(rm, __shfl_xor(rm, 8));
            float mn = fmaxf(m[r], rm);
            float alpha = __expf(m[r] - mn);
            m[r] = mn;
            float p0 = __expf(s0 - mn), p1 = __expf(s1 - mn);
            float rs = p0 + p1;
            rs += __shfl_xor(rs, 1);
            rs += __shfl_xor(rs, 2);
            rs += __shfl_xor(rs, 4);
            rs += __shfl_xor(rs, 8);
            l[r] = l[r] * alpha + rs;
            #pragma unroll
            for (int j = 0; j < 4; j++) o[j][r] *= alpha;
            p[0][r] = p0; p[1][r] = p1;
        }
        __syncthreads();
        #pragma unroll
        for (int tt = 0; tt < 2; tt++)
            #pragma unroll
            for (int r = 0; r < 4; r++)
                plds[(quad * 4 + r) * 40 + tt * 16 + l16] = (bf16_t)p[tt][r];
        __syncthreads();
        bf16x8 pf = ld8(&plds[l16 * 40 + quad * 8]);
        #pragma unroll
        for (int j = 0; j < 4; j++) {
            bf16x8 vf = ld8(vbase + (size_t)(j * 16 + l16) * SEQ + kb + quad * 8);
            o[j] = __builtin_amdgcn_mfma_f32_16x16x32_bf16(pf, vf, o[j], 0, 0, 0);
        }
    }
    #pragma unroll
    for (int j = 0; j < 4; j++) {
        #pragma unroll
        for (int r = 0; r < 4; r++) {
            int row = q0 + quad * 4 + r;
            int col = h * 64 + j * 16 + l16;
            out[((size_t)(b * SEQ) + row) * DIM + col] = (bf16_t)(o[j][r] / l[r]);
        }
    }
}

extern "C" void kernel_launch(void* const* d_in, const int* in_sizes, int n_in,
                              void* d_out, int out_size, void* d_ws, size_t ws_size,
                              hipStream_t stream) {
    const float* x     = (const float*)d_in[0];
    const float* ln1_w = (const float*)d_in[1];
    const float* ln1_b = (const float*)d_in[2];
    const float* w_qkv = (const float*)d_in[3];
    const float* w_o   = (const float*)d_in[4];
    const float* b_o   = (const float*)d_in[5];
    const float* ln2_w = (const float*)d_in[6];
    const float* ln2_b = (const float*)d_in[7];
    const float* w1    = (const float*)d_in[8];
    const float* b1    = (const float*)d_in[9];
    const float* w2    = (const float*)d_in[10];
    const float* b2    = (const float*)d_in[11];
    float* out = (float*)d_out;

    char* ws = (char*)d_ws;
    size_t off = 0;
    auto alloc = [&](size_t elems) -> bf16_t* {
        bf16_t* p = (bf16_t*)(ws + off);
        off += (elems * 2 + 255) & ~(size_t)255;
        return p;
    };
    bf16_t* wqkv_b = alloc((size_t)DEPTH * DIM * QKVN);
    bf16_t* wo_b   = alloc((size_t)DEPTH * DIM * DIM);
    bf16_t* w1_b   = alloc((size_t)DEPTH * DIM * MLPD);
    bf16_t* w2_b   = alloc((size_t)DEPTH * MLPD * DIM);
    bf16_t* hbuf   = alloc((size_t)MTOT * DIM);
    bf16_t* qkvb   = alloc((size_t)MTOT * QKVN);
    bf16_t* vtb    = alloc((size_t)BATCH * HEADS * 64 * SEQ);
    bf16_t* aob    = alloc((size_t)MTOT * DIM);
    bf16_t* midb   = alloc((size_t)MTOT * MLPD);
    if (off > ws_size) return;  // workspace insufficient — fail visibly

    auto cvt = [&](const float* src, bf16_t* dst, size_t n) {
        int n4 = (int)(n / 4);
        cvt4_kernel<<<(n4 + 255) / 256, 256, 0, stream>>>((const float4*)src, dst, n4);
    };
    cvt(w_qkv, wqkv_b, (size_t)DEPTH * DIM * QKVN);
    cvt(w_o,   wo_b,   (size_t)DEPTH * DIM * DIM);
    cvt(w1,    w1_b,   (size_t)DEPTH * DIM * MLPD);
    cvt(w2,    w2_b,   (size_t)DEPTH * MLPD * DIM);

    hipMemcpyAsync(out, x, (size_t)MTOT * DIM * 4, hipMemcpyDeviceToDevice, stream);

    for (int L = 0; L < DEPTH; L++) {
        ln_kernel<<<MTOT, 256, 0, stream>>>(out, ln1_w + L * DIM, ln1_b + L * DIM, hbuf);
        gemm_kernel<0><<<dim3(QKVN / 128, MTOT / 128), 256, 0, stream>>>(
            hbuf, wqkv_b + (size_t)L * DIM * QKVN, nullptr, qkvb, nullptr, QKVN, DIM);
        vtrans_kernel<<<dim3(16, BATCH * HEADS), 256, 0, stream>>>(qkvb, vtb);
        attn_kernel<<<dim3(SEQ / 16, HEADS, BATCH), 64, 0, stream>>>(qkvb, vtb, aob);
        gemm_kernel<2><<<dim3(DIM / 128, MTOT / 128), 256, 0, stream>>>(
            aob, wo_b + (size_t)L * DIM * DIM, b_o + L * DIM, nullptr, out, DIM, DIM);
        ln_kernel<<<MTOT, 256, 0, stream>>>(out, ln2_w + L * DIM, ln2_b + L * DIM, hbuf);
        gemm_kernel<1><<<dim3(MLPD / 128, MTOT / 128), 256, 0, stream>>>(
            hbuf, w1_b + (size_t)L * DIM * MLPD, b1 + L * MLPD, midb, nullptr, MLPD, DIM);
        gemm_kernel<2><<<dim3(DIM / 128, MTOT / 128), 256, 0, stream>>>(
            midb, w2_b + (size_t)L * MLPD * DIM, b2 + L * DIM, nullptr, out, DIM, MLPD);
    }
}

// Round 2
// 1829.896 us; speedup vs baseline: 1.1852x; 1.1852x over previous
//
#include <hip/hip_runtime.h>
#include <cmath>
#include <cstdint>

typedef __bf16 bf16_t;
typedef __bf16 bf16x8 __attribute__((ext_vector_type(8)));
typedef float  f32x4  __attribute__((ext_vector_type(4)));

#define DEPTH 6
#define DIM   768
#define HEADS 12
#define DH    64
#define MLPD  3072
#define SEQ   1024
#define BATCH 4
#define MTOT  (BATCH*SEQ)   /* 4096 rows */
#define QKVN  2304          /* 3*768 */

static __device__ __forceinline__ bf16x8 ld8(const bf16_t* p) {
    return *(const bf16x8*)p;
}

// async global->LDS, 16B per lane. LDS dest is wave-uniform base + lane*16
// (m104/m108 semantics) — caller passes the wave-uniform base.
typedef const __attribute__((address_space(1))) unsigned int gas_u32;
typedef __attribute__((address_space(3))) unsigned int las_u32;
static __device__ __forceinline__ void gload16(const bf16_t* g, bf16_t* l) {
    __builtin_amdgcn_global_load_lds((gas_u32*)g, (las_u32*)l, 16, 0, 0);
}

// ---------------- fp32 [K][N] -> bf16 [N][K] transposed weight ----------------
__global__ __launch_bounds__(256) void tcvt_kernel(const float* __restrict__ in,
                                                   bf16_t* __restrict__ out,
                                                   int K, int N) {
    __shared__ float ts[32][33];
    int n0 = blockIdx.x * 32, k0 = blockIdx.y * 32;
    size_t base = (size_t)blockIdx.z * K * N;
    int tx = threadIdx.x & 31, ty = threadIdx.x >> 5;   // 32 x 8
    #pragma unroll
    for (int r = 0; r < 32; r += 8)
        ts[ty + r][tx] = in[base + (size_t)(k0 + ty + r) * N + n0 + tx];
    __syncthreads();
    #pragma unroll
    for (int r = 0; r < 32; r += 8)
        out[base + (size_t)(n0 + ty + r) * K + k0 + tx] = (bf16_t)ts[tx][ty + r];
}

// ---------------- LayerNorm: fp32 x -> bf16 h ----------------
__global__ __launch_bounds__(256) void ln_kernel(const float* __restrict__ x,
                                                 const float* __restrict__ w,
                                                 const float* __restrict__ b,
                                                 bf16_t* __restrict__ h) {
    int row = blockIdx.x, t = threadIdx.x;
    const float* xr = x + (size_t)row * DIM;
    float v0 = xr[t], v1 = xr[t + 256], v2 = xr[t + 512];
    float s = v0 + v1 + v2;
    float q = v0 * v0 + v1 * v1 + v2 * v2;
    #pragma unroll
    for (int off = 32; off > 0; off >>= 1) {
        s += __shfl_down(s, off);
        q += __shfl_down(q, off);
    }
    __shared__ float ss[4], sq[4], stat[2];
    if ((t & 63) == 0) { ss[t >> 6] = s; sq[t >> 6] = q; }
    __syncthreads();
    if (t == 0) {
        float S = ss[0] + ss[1] + ss[2] + ss[3];
        float Q = sq[0] + sq[1] + sq[2] + sq[3];
        float mean = S * (1.0f / DIM);
        float var  = Q * (1.0f / DIM) - mean * mean;
        stat[0] = mean;
        stat[1] = rsqrtf(var + 1e-5f);
    }
    __syncthreads();
    float mean = stat[0], rstd = stat[1];
    bf16_t* hr = h + (size_t)row * DIM;
    hr[t]       = (bf16_t)((v0 - mean) * rstd * w[t]       + b[t]);
    hr[t + 256] = (bf16_t)((v1 - mean) * rstd * w[t + 256] + b[t + 256]);
    hr[t + 512] = (bf16_t)((v2 - mean) * rstd * w[t + 512] + b[t + 512]);
}

// ---------------- bf16 MFMA GEMM (m97 structure), C = A @ Bt^T ----------------
// A: [M][K] bf16, Bt: [N][K] bf16 (pre-transposed weight).
// 128x128 tile, BK=32, global_load_lds width-16 staging, unpadded LDS.
// EPI 0: Cb = A@B            (QKV)
// EPI 1: Cb = gelu(A@B+bias) (MLP1)
// EPI 2: atomicAdd(Cf, A@B + (kz==0)*bias)  (proj / MLP2, split-K residual)
template <int EPI>
__global__ __launch_bounds__(256) void gemm_kernel(const bf16_t* __restrict__ A,
                                                   const bf16_t* __restrict__ Bt,
                                                   const float* __restrict__ bias,
                                                   bf16_t* __restrict__ Cb,
                                                   float* __restrict__ Cf,
                                                   int N, int K, int klen) {
    __shared__ __align__(16) bf16_t As[128 * 32];
    __shared__ __align__(16) bf16_t Bs[128 * 32];
    int t = threadIdx.x;
    int m0 = blockIdx.y * 128, n0 = blockIdx.x * 128;
    int kz = blockIdx.z;
    int kbeg = kz * klen, kend = kbeg + klen;
    int lane = t & 63, l16 = lane & 15, quad = lane >> 4;
    int wv = t >> 6, wm = wv >> 1, wn = wv & 1;
    f32x4 acc[4][4] = {};

    // staging: wave wv covers rows wv*16..wv*16+15 of each 64-row half;
    // lane ln -> row wv*16 + ln/4, k-chunk (ln&3)*8 — matches base+lane*16.
    int srow = wv * 16 + (lane >> 2);
    int skc  = (lane & 3) * 8;
    const bf16_t* ga0 = A  + (size_t)(m0 + srow) * K + skc;
    const bf16_t* ga1 = ga0 + (size_t)64 * K;
    const bf16_t* gb0 = Bt + (size_t)(n0 + srow) * K + skc;
    const bf16_t* gb1 = gb0 + (size_t)64 * K;
    bf16_t* la0 = &As[(wv * 16) * 32];
    bf16_t* la1 = &As[(64 + wv * 16) * 32];
    bf16_t* lb0 = &Bs[(wv * 16) * 32];
    bf16_t* lb1 = &Bs[(64 + wv * 16) * 32];

    for (int k0 = kbeg; k0 < kend; k0 += 32) {
        __syncthreads();                 // prior frag reads done before overwrite
        gload16(ga0 + k0, la0);
        gload16(ga1 + k0, la1);
        gload16(gb0 + k0, lb0);
        gload16(gb1 + k0, lb1);
        __syncthreads();                 // vmcnt(0) drain: LDS data landed
        bf16x8 af[4], bfr[4];
        #pragma unroll
        for (int i = 0; i < 4; i++)
            af[i] = ld8(&As[(wm * 64 + i * 16 + l16) * 32 + quad * 8]);
        #pragma unroll
        for (int j = 0; j < 4; j++)
            bfr[j] = ld8(&Bs[(wn * 64 + j * 16 + l16) * 32 + quad * 8]);
        #pragma unroll
        for (int i = 0; i < 4; i++)
            #pragma unroll
            for (int j = 0; j < 4; j++)
                acc[i][j] = __builtin_amdgcn_mfma_f32_16x16x32_bf16(af[i], bfr[j], acc[i][j], 0, 0, 0);
    }

    #pragma unroll
    for (int i = 0; i < 4; i++) {
        int grow = m0 + wm * 64 + i * 16 + quad * 4;
        #pragma unroll
        for (int j = 0; j < 4; j++) {
            int gcol = n0 + wn * 64 + j * 16 + l16;
            float bv = 0.0f;
            if constexpr (EPI != 0) bv = bias[gcol];
            #pragma unroll
            for (int r = 0; r < 4; r++) {
                size_t idx = (size_t)(grow + r) * N + gcol;
                float v = acc[i][j][r];
                if constexpr (EPI == 0) {
                    Cb[idx] = (bf16_t)v;
                } else if constexpr (EPI == 1) {
                    v += bv;
                    v = 0.5f * v * (1.0f + erff(v * 0.70710678118654752f));
                    Cb[idx] = (bf16_t)v;
                } else {
                    float add = v + (blockIdx.z == 0 ? bv : 0.0f);
                    atomicAdd(&Cf[idx], add);
                }
            }
        }
    }
}

// ---------------- V transpose: qkv V-slice -> Vt[b][h][d][n] ----------------
__global__ __launch_bounds__(256) void vtrans_kernel(const bf16_t* __restrict__ qkv,
                                                     bf16_t* __restrict__ vt) {
    int nt = blockIdx.x;           // 16 tiles of 64 keys
    int bh = blockIdx.y;           // b*HEADS + h
    int b = bh / HEADS, h = bh % HEADS;
    __shared__ bf16_t ts[64 * 65];
    int t = threadIdx.x;
    #pragma unroll
    for (int s = 0; s < 16; s++) {
        int flat = s * 256 + t;
        int r = flat >> 6, d = flat & 63;
        ts[d * 65 + r] = qkv[((size_t)(b * SEQ) + nt * 64 + r) * QKVN + 1536 + h * 64 + d];
    }
    __syncthreads();
    #pragma unroll
    for (int s = 0; s < 16; s++) {
        int flat = s * 256 + t;
        int d = flat >> 6, c = flat & 63;
        vt[((size_t)bh * 64 + d) * SEQ + nt * 64 + c] = ts[d * 65 + c];
    }
}

// ---------------- flash attention: 4 waves/block, each wave owns 256 keys ----
// Per-wave online softmax over its key range; partials (m,l,o) merged in LDS.
__global__ __launch_bounds__(256) void attn_kernel(const bf16_t* __restrict__ qkv,
                                                   const bf16_t* __restrict__ vt,
                                                   bf16_t* __restrict__ out) {
    int qt = blockIdx.x, h = blockIdx.y, b = blockIdx.z;
    int t = threadIdx.x;
    int wv = t >> 6, lane = t & 63, l16 = lane & 15, quad = lane >> 4;
    int q0 = qt * 16;
    const bf16_t* qbase = qkv + ((size_t)(b * SEQ) + q0 + l16) * QKVN + h * 64;
    bf16x8 qf0 = ld8(qbase + quad * 8);
    bf16x8 qf1 = ld8(qbase + 32 + quad * 8);
    float m[4], l[4];
    f32x4 o[4] = {};
    #pragma unroll
    for (int r = 0; r < 4; r++) { m[r] = -1e30f; l[r] = 0.0f; }

    __shared__ __align__(16) bf16_t plds[4][16 * 40];
    __shared__ float mL[4][16], lL[4][16];
    __shared__ float oL[4][16][64];

    const bf16_t* kbase = qkv + ((size_t)(b * SEQ) + l16) * QKVN + 768 + h * 64;
    const bf16_t* vbase = vt + ((size_t)(b * HEADS + h) * 64) * SEQ;

    int kbeg = wv * 256, kendw = kbeg + 256;
    for (int kb = kbeg; kb < kendw; kb += 32) {
        f32x4 s[2];
        #pragma unroll
        for (int tt = 0; tt < 2; tt++) {
            const bf16_t* kp = kbase + (size_t)(kb + tt * 16) * QKVN;
            f32x4 z = {};
            z = __builtin_amdgcn_mfma_f32_16x16x32_bf16(qf0, ld8(kp + quad * 8), z, 0, 0, 0);
            z = __builtin_amdgcn_mfma_f32_16x16x32_bf16(qf1, ld8(kp + 32 + quad * 8), z, 0, 0, 0);
            s[tt] = z;
        }
        float p[2][4];
        #pragma unroll
        for (int r = 0; r < 4; r++) {
            float s0 = s[0][r] * 0.125f, s1 = s[1][r] * 0.125f;
            float rm = fmaxf(s0, s1);
            rm = fmaxf(rm, __shfl_xor(rm, 1));
            rm = fmaxf(rm, __shfl_xor(rm, 2));
            rm = fmaxf(rm, __shfl_xor(rm, 4));
            rm = fmaxf(rm, __shfl_xor(rm, 8));
            float mn = fmaxf(m[r], rm);
            float alpha = __expf(m[r] - mn);
            m[r] = mn;
            float p0 = __expf(s0 - mn), p1 = __expf(s1 - mn);
            float rs = p0 + p1;
            rs += __shfl_xor(rs, 1);
            rs += __shfl_xor(rs, 2);
            rs += __shfl_xor(rs, 4);
            rs += __shfl_xor(rs, 8);
            l[r] = l[r] * alpha + rs;
            #pragma unroll
            for (int j = 0; j < 4; j++) o[j][r] *= alpha;
            p[0][r] = p0; p[1][r] = p1;
        }
        __syncthreads();
        #pragma unroll
        for (int tt = 0; tt < 2; tt++)
            #pragma unroll
            for (int r = 0; r < 4; r++)
                plds[wv][(quad * 4 + r) * 40 + tt * 16 + l16] = (bf16_t)p[tt][r];
        __syncthreads();
        bf16x8 pf = ld8(&plds[wv][l16 * 40 + quad * 8]);
        #pragma unroll
        for (int j = 0; j < 4; j++) {
            bf16x8 vf = ld8(vbase + (size_t)(j * 16 + l16) * SEQ + kb + quad * 8);
            o[j] = __builtin_amdgcn_mfma_f32_16x16x32_bf16(pf, vf, o[j], 0, 0, 0);
        }
    }

    // publish per-wave partials
    if (l16 == 0) {
        #pragma unroll
        for (int r = 0; r < 4; r++) {
            mL[wv][quad * 4 + r] = m[r];
            lL[wv][quad * 4 + r] = l[r];
        }
    }
    #pragma unroll
    for (int j = 0; j < 4; j++)
        #pragma unroll
        for (int r = 0; r < 4; r++)
            oL[wv][quad * 4 + r][j * 16 + l16] = o[j][r];
    __syncthreads();

    // merge 4 wave-partials; 256 threads cover 16 rows x 64 cols, 4 each
    #pragma unroll
    for (int sft = 0; sft < 4; sft++) {
        int row = sft * 4 + (t >> 6);
        int col = t & 63;
        float M = fmaxf(fmaxf(mL[0][row], mL[1][row]), fmaxf(mL[2][row], mL[3][row]));
        float O = 0.0f, Ls = 0.0f;
        #pragma unroll
        for (int w = 0; w < 4; w++) {
            float a = __expf(mL[w][row] - M);
            O  += oL[w][row][col] * a;
            Ls += lL[w][row] * a;
        }
        out[((size_t)(b * SEQ) + q0 + row) * DIM + h * 64 + col] = (bf16_t)(O / Ls);
    }
}

extern "C" void kernel_launch(void* const* d_in, const int* in_sizes, int n_in,
                              void* d_out, int out_size, void* d_ws, size_t ws_size,
                              hipStream_t stream) {
    const float* x     = (const float*)d_in[0];
    const float* ln1_w = (const float*)d_in[1];
    const float* ln1_b = (const float*)d_in[2];
    const float* w_qkv = (const float*)d_in[3];
    const float* w_o   = (const float*)d_in[4];
    const float* b_o   = (const float*)d_in[5];
    const float* ln2_w = (const float*)d_in[6];
    const float* ln2_b = (const float*)d_in[7];
    const float* w1    = (const float*)d_in[8];
    const float* b1    = (const float*)d_in[9];
    const float* w2    = (const float*)d_in[10];
    const float* b2    = (const float*)d_in[11];
    float* out = (float*)d_out;

    char* ws = (char*)d_ws;
    size_t off = 0;
    auto alloc = [&](size_t elems) -> bf16_t* {
        bf16_t* p = (bf16_t*)(ws + off);
        off += (elems * 2 + 255) & ~(size_t)255;
        return p;
    };
    bf16_t* wqkv_t = alloc((size_t)DEPTH * DIM * QKVN);   // [L][2304][768]
    bf16_t* wo_t   = alloc((size_t)DEPTH * DIM * DIM);    // [L][768][768]
    bf16_t* w1_t   = alloc((size_t)DEPTH * DIM * MLPD);   // [L][3072][768]
    bf16_t* w2_t   = alloc((size_t)DEPTH * MLPD * DIM);   // [L][768][3072]
    bf16_t* hbuf   = alloc((size_t)MTOT * DIM);
    bf16_t* qkvb   = alloc((size_t)MTOT * QKVN);
    bf16_t* vtb    = alloc((size_t)BATCH * HEADS * 64 * SEQ);
    bf16_t* aob    = alloc((size_t)MTOT * DIM);
    bf16_t* midb   = alloc((size_t)MTOT * MLPD);
    if (off > ws_size) return;  // workspace insufficient — fail visibly

    // weights: fp32 [K][N] -> bf16 [N][K]
    tcvt_kernel<<<dim3(QKVN / 32, DIM / 32, DEPTH), 256, 0, stream>>>(w_qkv, wqkv_t, DIM, QKVN);
    tcvt_kernel<<<dim3(DIM / 32,  DIM / 32, DEPTH), 256, 0, stream>>>(w_o,   wo_t,   DIM, DIM);
    tcvt_kernel<<<dim3(MLPD / 32, DIM / 32, DEPTH), 256, 0, stream>>>(w1,    w1_t,   DIM, MLPD);
    tcvt_kernel<<<dim3(DIM / 32, MLPD / 32, DEPTH), 256, 0, stream>>>(w2,    w2_t,   MLPD, DIM);

    hipMemcpyAsync(out, x, (size_t)MTOT * DIM * 4, hipMemcpyDeviceToDevice, stream);

    for (int L = 0; L < DEPTH; L++) {
        ln_kernel<<<MTOT, 256, 0, stream>>>(out, ln1_w + L * DIM, ln1_b + L * DIM, hbuf);
        gemm_kernel<0><<<dim3(QKVN / 128, MTOT / 128, 1), 256, 0, stream>>>(
            hbuf, wqkv_t + (size_t)L * DIM * QKVN, nullptr, qkvb, nullptr, QKVN, DIM, DIM);
        vtrans_kernel<<<dim3(16, BATCH * HEADS), 256, 0, stream>>>(qkvb, vtb);
        attn_kernel<<<dim3(SEQ / 16, HEADS, BATCH), 256, 0, stream>>>(qkvb, vtb, aob);
        // proj: N=768, K=768, split-K x2 -> 384 blocks
        gemm_kernel<2><<<dim3(DIM / 128, MTOT / 128, 2), 256, 0, stream>>>(
            aob, wo_t + (size_t)L * DIM * DIM, b_o + L * DIM, nullptr, out, DIM, DIM, 384);
        ln_kernel<<<MTOT, 256, 0, stream>>>(out, ln2_w + L * DIM, ln2_b + L * DIM, hbuf);
        gemm_kernel<1><<<dim3(MLPD / 128, MTOT / 128, 1), 256, 0, stream>>>(
            hbuf, w1_t + (size_t)L * DIM * MLPD, b1 + L * MLPD, midb, nullptr, MLPD, DIM, DIM);
        // MLP2: N=768, K=3072, split-K x4 -> 768 blocks
        gemm_kernel<2><<<dim3(DIM / 128, MTOT / 128, 4), 256, 0, stream>>>(
            midb, w2_t + (size_t)L * MLPD * DIM, b2 + L * DIM, nullptr, out, DIM, MLPD, 768);
    }
}

// Round 3
// 1828.598 us; speedup vs baseline: 1.1861x; 1.0007x over previous
//
#include <hip/hip_runtime.h>
#include <cmath>
#include <cstdint>

typedef __bf16 bf16_t;
typedef __bf16 bf16x8 __attribute__((ext_vector_type(8)));
typedef __bf16 bf16x4 __attribute__((ext_vector_type(4)));
typedef float  f32x4  __attribute__((ext_vector_type(4)));

#define DEPTH 6
#define DIM   768
#define HEADS 12
#define DH    64
#define MLPD  3072
#define SEQ   1024
#define BATCH 4
#define MTOT  (BATCH*SEQ)   /* 4096 rows */
#define QKVN  2304          /* 3*768 */

static __device__ __forceinline__ bf16x8 ld8(const bf16_t* p) {
    return *(const bf16x8*)p;
}

// async global->LDS, 16B per lane. LDS dest is wave-uniform base + lane*16.
typedef const __attribute__((address_space(1))) unsigned int gas_u32;
typedef __attribute__((address_space(3))) unsigned int las_u32;
static __device__ __forceinline__ void gload16(const bf16_t* g, bf16_t* l) {
    __builtin_amdgcn_global_load_lds((gas_u32*)g, (las_u32*)l, 16, 0, 0);
}

// ---------------- fp32 [K][N] -> bf16 [N][K] transposed weight ----------------
__global__ __launch_bounds__(256) void tcvt_kernel(const float* __restrict__ in,
                                                   bf16_t* __restrict__ out,
                                                   int K, int N) {
    __shared__ float ts[32][33];
    int n0 = blockIdx.x * 32, k0 = blockIdx.y * 32;
    size_t base = (size_t)blockIdx.z * K * N;
    int tx = threadIdx.x & 31, ty = threadIdx.x >> 5;   // 32 x 8
    #pragma unroll
    for (int r = 0; r < 32; r += 8)
        ts[ty + r][tx] = in[base + (size_t)(k0 + ty + r) * N + n0 + tx];
    __syncthreads();
    #pragma unroll
    for (int r = 0; r < 32; r += 8)
        out[base + (size_t)(n0 + ty + r) * K + k0 + tx] = (bf16_t)ts[tx][ty + r];
}

// ---------------- LayerNorm: fp32 x -> bf16 h ----------------
__global__ __launch_bounds__(256) void ln_kernel(const float* __restrict__ x,
                                                 const float* __restrict__ w,
                                                 const float* __restrict__ b,
                                                 bf16_t* __restrict__ h) {
    int row = blockIdx.x, t = threadIdx.x;
    const float* xr = x + (size_t)row * DIM;
    float v0 = xr[t], v1 = xr[t + 256], v2 = xr[t + 512];
    float s = v0 + v1 + v2;
    float q = v0 * v0 + v1 * v1 + v2 * v2;
    #pragma unroll
    for (int off = 32; off > 0; off >>= 1) {
        s += __shfl_down(s, off);
        q += __shfl_down(q, off);
    }
    __shared__ float ss[4], sq[4], stat[2];
    if ((t & 63) == 0) { ss[t >> 6] = s; sq[t >> 6] = q; }
    __syncthreads();
    if (t == 0) {
        float S = ss[0] + ss[1] + ss[2] + ss[3];
        float Q = sq[0] + sq[1] + sq[2] + sq[3];
        float mean = S * (1.0f / DIM);
        float var  = Q * (1.0f / DIM) - mean * mean;
        stat[0] = mean;
        stat[1] = rsqrtf(var + 1e-5f);
    }
    __syncthreads();
    float mean = stat[0], rstd = stat[1];
    bf16_t* hr = h + (size_t)row * DIM;
    hr[t]       = (bf16_t)((v0 - mean) * rstd * w[t]       + b[t]);
    hr[t + 256] = (bf16_t)((v1 - mean) * rstd * w[t + 256] + b[t + 256]);
    hr[t + 512] = (bf16_t)((v2 - mean) * rstd * w[t + 512] + b[t + 512]);
}

// ---------------- bf16 MFMA GEMM (m97 structure), C = A @ Bt^T ----------------
template <int EPI>
__global__ __launch_bounds__(256) void gemm_kernel(const bf16_t* __restrict__ A,
                                                   const bf16_t* __restrict__ Bt,
                                                   const float* __restrict__ bias,
                                                   bf16_t* __restrict__ Cb,
                                                   float* __restrict__ Cf,
                                                   int N, int K, int klen) {
    __shared__ __align__(16) bf16_t As[128 * 32];
    __shared__ __align__(16) bf16_t Bs[128 * 32];
    int t = threadIdx.x;
    int m0 = blockIdx.y * 128, n0 = blockIdx.x * 128;
    int kz = blockIdx.z;
    int kbeg = kz * klen, kend = kbeg + klen;
    int lane = t & 63, l16 = lane & 15, quad = lane >> 4;
    int wv = t >> 6, wm = wv >> 1, wn = wv & 1;
    f32x4 acc[4][4] = {};

    int srow = wv * 16 + (lane >> 2);
    int skc  = (lane & 3) * 8;
    const bf16_t* ga0 = A  + (size_t)(m0 + srow) * K + skc;
    const bf16_t* ga1 = ga0 + (size_t)64 * K;
    const bf16_t* gb0 = Bt + (size_t)(n0 + srow) * K + skc;
    const bf16_t* gb1 = gb0 + (size_t)64 * K;
    bf16_t* la0 = &As[(wv * 16) * 32];
    bf16_t* la1 = &As[(64 + wv * 16) * 32];
    bf16_t* lb0 = &Bs[(wv * 16) * 32];
    bf16_t* lb1 = &Bs[(64 + wv * 16) * 32];

    for (int k0 = kbeg; k0 < kend; k0 += 32) {
        __syncthreads();
        gload16(ga0 + k0, la0);
        gload16(ga1 + k0, la1);
        gload16(gb0 + k0, lb0);
        gload16(gb1 + k0, lb1);
        __syncthreads();
        bf16x8 af[4], bfr[4];
        #pragma unroll
        for (int i = 0; i < 4; i++)
            af[i] = ld8(&As[(wm * 64 + i * 16 + l16) * 32 + quad * 8]);
        #pragma unroll
        for (int j = 0; j < 4; j++)
            bfr[j] = ld8(&Bs[(wn * 64 + j * 16 + l16) * 32 + quad * 8]);
        #pragma unroll
        for (int i = 0; i < 4; i++)
            #pragma unroll
            for (int j = 0; j < 4; j++)
                acc[i][j] = __builtin_amdgcn_mfma_f32_16x16x32_bf16(af[i], bfr[j], acc[i][j], 0, 0, 0);
    }

    #pragma unroll
    for (int i = 0; i < 4; i++) {
        int grow = m0 + wm * 64 + i * 16 + quad * 4;
        #pragma unroll
        for (int j = 0; j < 4; j++) {
            int gcol = n0 + wn * 64 + j * 16 + l16;
            float bv = 0.0f;
            if constexpr (EPI != 0) bv = bias[gcol];
            #pragma unroll
            for (int r = 0; r < 4; r++) {
                size_t idx = (size_t)(grow + r) * N + gcol;
                float v = acc[i][j][r];
                if constexpr (EPI == 0) {
                    Cb[idx] = (bf16_t)v;
                } else if constexpr (EPI == 1) {
                    v += bv;
                    v = 0.5f * v * (1.0f + erff(v * 0.70710678118654752f));
                    Cb[idx] = (bf16_t)v;
                } else {
                    float add = v + (blockIdx.z == 0 ? bv : 0.0f);
                    atomicAdd(&Cf[idx], add);
                }
            }
        }
    }
}

// ---------------- V transpose: qkv V-slice -> Vt[b][h][d][n] ----------------
__global__ __launch_bounds__(256) void vtrans_kernel(const bf16_t* __restrict__ qkv,
                                                     bf16_t* __restrict__ vt) {
    int nt = blockIdx.x;
    int bh = blockIdx.y;
    int b = bh / HEADS, h = bh % HEADS;
    __shared__ bf16_t ts[64 * 65];
    int t = threadIdx.x;
    #pragma unroll
    for (int s = 0; s < 16; s++) {
        int flat = s * 256 + t;
        int r = flat >> 6, d = flat & 63;
        ts[d * 65 + r] = qkv[((size_t)(b * SEQ) + nt * 64 + r) * QKVN + 1536 + h * 64 + d];
    }
    __syncthreads();
    #pragma unroll
    for (int s = 0; s < 16; s++) {
        int flat = s * 256 + t;
        int d = flat >> 6, c = flat & 63;
        vt[((size_t)bh * 64 + d) * SEQ + nt * 64 + c] = ts[d * 65 + c];
    }
}

// ---------------- flash attention v2: transposed scores (lane = query) -------
// S^T = K@Q^T  (A=K-frag, B=Q-frag) -> C: lane&15=query, quad*4+r=key
// O^T = V^T@P^T (A=Vt-frag, B=P-frag) -> C: lane&15=query, quad*4+r=dim
// Softmax reductions in-register + 2 shfl_xor per 64-key chunk; no barriers
// in the key loop (per-wave LDS slices, DS in-order per wave).
__global__ __launch_bounds__(256) void attn_kernel(const bf16_t* __restrict__ qkv,
                                                   const bf16_t* __restrict__ vt,
                                                   bf16_t* __restrict__ out) {
    int qt = blockIdx.x, h = blockIdx.y, b = blockIdx.z;
    int t = threadIdx.x;
    int wv = t >> 6, lane = t & 63, l16 = lane & 15, quad = lane >> 4;
    int q0 = qt * 16;
    const float LOG2E = 1.44269504f;

    // per-wave arena: keys-loop P buffer (16x72 bf16) unioned with merge
    // buffer (16x72 f32) — same wave's slice only, so no cross-wave hazard.
    __shared__ __align__(16) char arena[4][16 * 72 * 4];
    __shared__ float mLs[4][16], lLs[4][16];
    bf16_t* plds = (bf16_t*)arena[wv];

    // Q fragment (B operand): n=lane&15=query, k=quad*8+j over dims
    const bf16_t* qbase = qkv + ((size_t)(b * SEQ) + q0 + l16) * QKVN + h * 64;
    bf16x8 qf0 = ld8(qbase + quad * 8);
    bf16x8 qf1 = ld8(qbase + 32 + quad * 8);

    float m = -3e38f, l = 0.0f;
    f32x4 o[4] = {};   // o[j][r]: query=l16, dim=j*16+quad*4+r

    const bf16_t* kbase = qkv + ((size_t)(b * SEQ) + l16) * QKVN + 768 + h * 64;
    const bf16_t* vbase = vt + ((size_t)(b * HEADS + h) * 64) * SEQ;

    for (int kb = wv * 256; kb < wv * 256 + 256; kb += 64) {
        // scores^T for 64 keys: 4 tiles of 16
        f32x4 s[4];
        #pragma unroll
        for (int tt = 0; tt < 4; tt++) {
            const bf16_t* kp = kbase + (size_t)(kb + tt * 16) * QKVN;
            f32x4 z = {};
            z = __builtin_amdgcn_mfma_f32_16x16x32_bf16(ld8(kp + quad * 8), qf0, z, 0, 0, 0);
            z = __builtin_amdgcn_mfma_f32_16x16x32_bf16(ld8(kp + 32 + quad * 8), qf1, z, 0, 0, 0);
            s[tt] = z;   // s[tt][r]: key = kb+16*tt+4*quad+r, query = l16
        }
        float mx = -3e38f;
        #pragma unroll
        for (int tt = 0; tt < 4; tt++)
            #pragma unroll
            for (int r = 0; r < 4; r++) {
                s[tt][r] *= 0.125f;
                mx = fmaxf(mx, s[tt][r]);
            }
        mx = fmaxf(mx, __shfl_xor(mx, 16));
        mx = fmaxf(mx, __shfl_xor(mx, 32));
        float mn = fmaxf(m, mx);
        float alpha = exp2f((m - mn) * LOG2E);
        m = mn;
        float nb = mn * LOG2E;
        float rs = 0.0f;
        #pragma unroll
        for (int tt = 0; tt < 4; tt++) {
            bf16x4 pkt;
            #pragma unroll
            for (int r = 0; r < 4; r++) {
                float p = exp2f(fmaf(s[tt][r], LOG2E, -nb));
                rs += p;
                pkt[r] = (bf16_t)p;
            }
            *(bf16x4*)&plds[l16 * 72 + 16 * tt + 4 * quad] = pkt;
        }
        l = l * alpha + rs;          // quad-partial row sum; reduced at end
        #pragma unroll
        for (int j = 0; j < 4; j++) o[j] *= alpha;
        asm volatile("s_waitcnt lgkmcnt(0)" ::: "memory");  // P writes visible
        bf16x8 pf0 = ld8(&plds[l16 * 72 + quad * 8]);
        bf16x8 pf1 = ld8(&plds[l16 * 72 + 32 + quad * 8]);
        #pragma unroll
        for (int j = 0; j < 4; j++) {
            const bf16_t* vp = vbase + (size_t)(j * 16 + l16) * SEQ + kb;
            o[j] = __builtin_amdgcn_mfma_f32_16x16x32_bf16(ld8(vp + quad * 8), pf0, o[j], 0, 0, 0);
            o[j] = __builtin_amdgcn_mfma_f32_16x16x32_bf16(ld8(vp + 32 + quad * 8), pf1, o[j], 0, 0, 0);
        }
    }

    // publish per-wave partials (oL unions plds — same wave's slice)
    l += __shfl_xor(l, 16);
    l += __shfl_xor(l, 32);
    float* oLw = (float*)arena[wv];
    #pragma unroll
    for (int j = 0; j < 4; j++)
        *(f32x4*)&oLw[l16 * 72 + j * 16 + quad * 4] = o[j];
    if (quad == 0) { mLs[wv][l16] = m; lLs[wv][l16] = l; }
    __syncthreads();

    // merge 4 wave partials; 256 threads = 4 rows x 64 cols, 4 rows each
    int col = t & 63, rb = t >> 6;
    #pragma unroll
    for (int i = 0; i < 4; i++) {
        int row = rb * 4 + i;
        float M = fmaxf(fmaxf(mLs[0][row], mLs[1][row]), fmaxf(mLs[2][row], mLs[3][row]));
        float O = 0.0f, Ls = 0.0f;
        #pragma unroll
        for (int w = 0; w < 4; w++) {
            float a = exp2f((mLs[w][row] - M) * LOG2E);
            O  += ((const float*)arena[w])[row * 72 + col] * a;
            Ls += lLs[w][row] * a;
        }
        out[((size_t)(b * SEQ) + q0 + row) * DIM + h * 64 + col] = (bf16_t)(O / Ls);
    }
}

extern "C" void kernel_launch(void* const* d_in, const int* in_sizes, int n_in,
                              void* d_out, int out_size, void* d_ws, size_t ws_size,
                              hipStream_t stream) {
    const float* x     = (const float*)d_in[0];
    const float* ln1_w = (const float*)d_in[1];
    const float* ln1_b = (const float*)d_in[2];
    const float* w_qkv = (const float*)d_in[3];
    const float* w_o   = (const float*)d_in[4];
    const float* b_o   = (const float*)d_in[5];
    const float* ln2_w = (const float*)d_in[6];
    const float* ln2_b = (const float*)d_in[7];
    const float* w1    = (const float*)d_in[8];
    const float* b1    = (const float*)d_in[9];
    const float* w2    = (const float*)d_in[10];
    const float* b2    = (const float*)d_in[11];
    float* out = (float*)d_out;

    char* ws = (char*)d_ws;
    size_t off = 0;
    auto alloc = [&](size_t elems) -> bf16_t* {
        bf16_t* p = (bf16_t*)(ws + off);
        off += (elems * 2 + 255) & ~(size_t)255;
        return p;
    };
    bf16_t* wqkv_t = alloc((size_t)DEPTH * DIM * QKVN);
    bf16_t* wo_t   = alloc((size_t)DEPTH * DIM * DIM);
    bf16_t* w1_t   = alloc((size_t)DEPTH * DIM * MLPD);
    bf16_t* w2_t   = alloc((size_t)DEPTH * MLPD * DIM);
    bf16_t* hbuf   = alloc((size_t)MTOT * DIM);
    bf16_t* qkvb   = alloc((size_t)MTOT * QKVN);
    bf16_t* vtb    = alloc((size_t)BATCH * HEADS * 64 * SEQ);
    bf16_t* aob    = alloc((size_t)MTOT * DIM);
    bf16_t* midb   = alloc((size_t)MTOT * MLPD);
    if (off > ws_size) return;

    tcvt_kernel<<<dim3(QKVN / 32, DIM / 32, DEPTH), 256, 0, stream>>>(w_qkv, wqkv_t, DIM, QKVN);
    tcvt_kernel<<<dim3(DIM / 32,  DIM / 32, DEPTH), 256, 0, stream>>>(w_o,   wo_t,   DIM, DIM);
    tcvt_kernel<<<dim3(MLPD / 32, DIM / 32, DEPTH), 256, 0, stream>>>(w1,    w1_t,   DIM, MLPD);
    tcvt_kernel<<<dim3(DIM / 32, MLPD / 32, DEPTH), 256, 0, stream>>>(w2,    w2_t,   MLPD, DIM);

    hipMemcpyAsync(out, x, (size_t)MTOT * DIM * 4, hipMemcpyDeviceToDevice, stream);

    for (int L = 0; L < DEPTH; L++) {
        ln_kernel<<<MTOT, 256, 0, stream>>>(out, ln1_w + L * DIM, ln1_b + L * DIM, hbuf);
        gemm_kernel<0><<<dim3(QKVN / 128, MTOT / 128, 1), 256, 0, stream>>>(
            hbuf, wqkv_t + (size_t)L * DIM * QKVN, nullptr, qkvb, nullptr, QKVN, DIM, DIM);
        vtrans_kernel<<<dim3(16, BATCH * HEADS), 256, 0, stream>>>(qkvb, vtb);
        attn_kernel<<<dim3(SEQ / 16, HEADS, BATCH), 256, 0, stream>>>(qkvb, vtb, aob);
        gemm_kernel<2><<<dim3(DIM / 128, MTOT / 128, 2), 256, 0, stream>>>(
            aob, wo_t + (size_t)L * DIM * DIM, b_o + L * DIM, nullptr, out, DIM, DIM, 384);
        ln_kernel<<<MTOT, 256, 0, stream>>>(out, ln2_w + L * DIM, ln2_b + L * DIM, hbuf);
        gemm_kernel<1><<<dim3(MLPD / 128, MTOT / 128, 1), 256, 0, stream>>>(
            hbuf, w1_t + (size_t)L * DIM * MLPD, b1 + L * MLPD, midb, nullptr, MLPD, DIM, DIM);
        gemm_kernel<2><<<dim3(DIM / 128, MTOT / 128, 4), 256, 0, stream>>>(
            midb, w2_t + (size_t)L * MLPD * DIM, b2 + L * DIM, nullptr, out, DIM, MLPD, 768);
    }
}

// Round 4
// 1505.365 us; speedup vs baseline: 1.4408x; 1.2147x over previous
//
#include <hip/hip_runtime.h>
#include <cmath>
#include <cstdint>

typedef __bf16 bf16_t;
typedef __bf16 bf16x8 __attribute__((ext_vector_type(8)));
typedef __bf16 bf16x4 __attribute__((ext_vector_type(4)));
typedef float  f32x4  __attribute__((ext_vector_type(4)));

#define DEPTH 6
#define DIM   768
#define HEADS 12
#define DH    64
#define MLPD  3072
#define SEQ   1024
#define BATCH 4
#define MTOT  (BATCH*SEQ)   /* 4096 rows */
#define QKVN  2304          /* 3*768 */

static __device__ __forceinline__ bf16x8 ld8(const bf16_t* p) {
    return *(const bf16x8*)p;
}

// async global->LDS, 16B per lane. LDS dest is wave-uniform base + lane*16.
typedef const __attribute__((address_space(1))) unsigned int gas_u32;
typedef __attribute__((address_space(3))) unsigned int las_u32;
static __device__ __forceinline__ void gload16(const bf16_t* g, bf16_t* l) {
    __builtin_amdgcn_global_load_lds((gas_u32*)g, (las_u32*)l, 16, 0, 0);
}

// ---------------- fp32 [K][N] -> bf16 [N][K] transposed weight ----------------
__global__ __launch_bounds__(256) void tcvt_kernel(const float* __restrict__ in,
                                                   bf16_t* __restrict__ out,
                                                   int K, int N) {
    __shared__ float ts[32][33];
    int n0 = blockIdx.x * 32, k0 = blockIdx.y * 32;
    size_t base = (size_t)blockIdx.z * K * N;
    int tx = threadIdx.x & 31, ty = threadIdx.x >> 5;   // 32 x 8
    #pragma unroll
    for (int r = 0; r < 32; r += 8)
        ts[ty + r][tx] = in[base + (size_t)(k0 + ty + r) * N + n0 + tx];
    __syncthreads();
    #pragma unroll
    for (int r = 0; r < 32; r += 8)
        out[base + (size_t)(n0 + ty + r) * K + k0 + tx] = (bf16_t)ts[tx][ty + r];
}

// ---------------- LayerNorm: fp32 x -> bf16 h ----------------
__global__ __launch_bounds__(256) void ln_kernel(const float* __restrict__ x,
                                                 const float* __restrict__ w,
                                                 const float* __restrict__ b,
                                                 bf16_t* __restrict__ h) {
    int row = blockIdx.x, t = threadIdx.x;
    const float* xr = x + (size_t)row * DIM;
    float v0 = xr[t], v1 = xr[t + 256], v2 = xr[t + 512];
    float s = v0 + v1 + v2;
    float q = v0 * v0 + v1 * v1 + v2 * v2;
    #pragma unroll
    for (int off = 32; off > 0; off >>= 1) {
        s += __shfl_down(s, off);
        q += __shfl_down(q, off);
    }
    __shared__ float ss[4], sq[4], stat[2];
    if ((t & 63) == 0) { ss[t >> 6] = s; sq[t >> 6] = q; }
    __syncthreads();
    if (t == 0) {
        float S = ss[0] + ss[1] + ss[2] + ss[3];
        float Q = sq[0] + sq[1] + sq[2] + sq[3];
        float mean = S * (1.0f / DIM);
        float var  = Q * (1.0f / DIM) - mean * mean;
        stat[0] = mean;
        stat[1] = rsqrtf(var + 1e-5f);
    }
    __syncthreads();
    float mean = stat[0], rstd = stat[1];
    bf16_t* hr = h + (size_t)row * DIM;
    hr[t]       = (bf16_t)((v0 - mean) * rstd * w[t]       + b[t]);
    hr[t + 256] = (bf16_t)((v1 - mean) * rstd * w[t + 256] + b[t + 256]);
    hr[t + 512] = (bf16_t)((v2 - mean) * rstd * w[t + 512] + b[t + 512]);
}

// ---------------- bf16 MFMA GEMM (m97 structure), C = A @ Bt^T ----------------
template <int EPI>
__global__ __launch_bounds__(256) void gemm_kernel(const bf16_t* __restrict__ A,
                                                   const bf16_t* __restrict__ Bt,
                                                   const float* __restrict__ bias,
                                                   bf16_t* __restrict__ Cb,
                                                   float* __restrict__ Cf,
                                                   int N, int K, int klen) {
    __shared__ __align__(16) bf16_t As[128 * 32];
    __shared__ __align__(16) bf16_t Bs[128 * 32];
    int t = threadIdx.x;
    int m0 = blockIdx.y * 128, n0 = blockIdx.x * 128;
    int kz = blockIdx.z;
    int kbeg = kz * klen, kend = kbeg + klen;
    int lane = t & 63, l16 = lane & 15, quad = lane >> 4;
    int wv = t >> 6, wm = wv >> 1, wn = wv & 1;
    f32x4 acc[4][4] = {};

    int srow = wv * 16 + (lane >> 2);
    int skc  = (lane & 3) * 8;
    const bf16_t* ga0 = A  + (size_t)(m0 + srow) * K + skc;
    const bf16_t* ga1 = ga0 + (size_t)64 * K;
    const bf16_t* gb0 = Bt + (size_t)(n0 + srow) * K + skc;
    const bf16_t* gb1 = gb0 + (size_t)64 * K;
    bf16_t* la0 = &As[(wv * 16) * 32];
    bf16_t* la1 = &As[(64 + wv * 16) * 32];
    bf16_t* lb0 = &Bs[(wv * 16) * 32];
    bf16_t* lb1 = &Bs[(64 + wv * 16) * 32];

    for (int k0 = kbeg; k0 < kend; k0 += 32) {
        __syncthreads();
        gload16(ga0 + k0, la0);
        gload16(ga1 + k0, la1);
        gload16(gb0 + k0, lb0);
        gload16(gb1 + k0, lb1);
        __syncthreads();
        bf16x8 af[4], bfr[4];
        #pragma unroll
        for (int i = 0; i < 4; i++)
            af[i] = ld8(&As[(wm * 64 + i * 16 + l16) * 32 + quad * 8]);
        #pragma unroll
        for (int j = 0; j < 4; j++)
            bfr[j] = ld8(&Bs[(wn * 64 + j * 16 + l16) * 32 + quad * 8]);
        #pragma unroll
        for (int i = 0; i < 4; i++)
            #pragma unroll
            for (int j = 0; j < 4; j++)
                acc[i][j] = __builtin_amdgcn_mfma_f32_16x16x32_bf16(af[i], bfr[j], acc[i][j], 0, 0, 0);
    }

    #pragma unroll
    for (int i = 0; i < 4; i++) {
        int grow = m0 + wm * 64 + i * 16 + quad * 4;
        #pragma unroll
        for (int j = 0; j < 4; j++) {
            int gcol = n0 + wn * 64 + j * 16 + l16;
            float bv = 0.0f;
            if constexpr (EPI != 0) bv = bias[gcol];
            #pragma unroll
            for (int r = 0; r < 4; r++) {
                size_t idx = (size_t)(grow + r) * N + gcol;
                float v = acc[i][j][r];
                if constexpr (EPI == 0) {
                    Cb[idx] = (bf16_t)v;
                } else if constexpr (EPI == 1) {
                    v += bv;
                    v = 0.5f * v * (1.0f + erff(v * 0.70710678118654752f));
                    Cb[idx] = (bf16_t)v;
                } else {
                    float add = v + (blockIdx.z == 0 ? bv : 0.0f);
                    atomicAdd(&Cf[idx], add);
                }
            }
        }
    }
}

// ---------------- V transpose: qkv V-slice -> Vt[b][h][d][n] ----------------
__global__ __launch_bounds__(256) void vtrans_kernel(const bf16_t* __restrict__ qkv,
                                                     bf16_t* __restrict__ vt) {
    int nt = blockIdx.x;
    int bh = blockIdx.y;
    int b = bh / HEADS, h = bh % HEADS;
    __shared__ bf16_t ts[64 * 65];
    int t = threadIdx.x;
    #pragma unroll
    for (int s = 0; s < 16; s++) {
        int flat = s * 256 + t;
        int r = flat >> 6, d = flat & 63;
        ts[d * 65 + r] = qkv[((size_t)(b * SEQ) + nt * 64 + r) * QKVN + 1536 + h * 64 + d];
    }
    __syncthreads();
    #pragma unroll
    for (int s = 0; s < 16; s++) {
        int flat = s * 256 + t;
        int d = flat >> 6, c = flat & 63;
        vt[((size_t)bh * 64 + d) * SEQ + nt * 64 + c] = ts[d * 65 + c];
    }
}

// ---------------- flash attention v3: LDS-staged K/V shared by 4 waves ------
// Block = (b, h, 64 queries); wave wv owns queries wv*16..wv*16+15 over the
// FULL key range (no cross-wave merge). Per 64-key chunk: waves 0-1 stage K
// into 2 dim-planes [64keys][32dims], waves 2-3 stage V^T [64dims][64keys],
// all via global_load_lds w=16 (LDS dest uniform+lane*16 — layouts chosen to
// match). m97 2-barrier structure.
// S^T = K@Q^T -> C: l16=query, quad*4+r=key. O^T = V^T@P^T -> l16=query,
// quad*4+r=dim. Softmax in-register, 2 shfl_xor per chunk.
__global__ __launch_bounds__(256) void attn_kernel(const bf16_t* __restrict__ qkv,
                                                   const bf16_t* __restrict__ vt,
                                                   bf16_t* __restrict__ out) {
    int qt = blockIdx.x, h = blockIdx.y, b = blockIdx.z;
    int t = threadIdx.x;
    int wv = t >> 6, lane = t & 63, l16 = lane & 15, quad = lane >> 4;
    const float LOG2E = 1.44269504f;
    int qw0 = qt * 64 + wv * 16;

    __shared__ __align__(16) bf16_t Ks[2][64 * 32];  // [plane][key][dim&31]
    __shared__ __align__(16) bf16_t Vs[64 * 64];     // [dim][key]
    __shared__ __align__(16) bf16_t Pa[4][16 * 72];  // per-wave P^T [query][key]
    bf16_t* P = Pa[wv];

    size_t bS = (size_t)b * SEQ;
    const bf16_t* qrow = qkv + (bS + qw0 + l16) * QKVN + h * 64;
    bf16x8 qf0 = ld8(qrow + quad * 8);        // dims 0..31
    bf16x8 qf1 = ld8(qrow + 32 + quad * 8);   // dims 32..63

    float m = -3e38f, l = 0.0f;
    f32x4 o[4] = {};   // o[jt][r]: query=l16, dim=jt*16+quad*4+r

    const bf16_t* kbase = qkv + bS * QKVN + 768 + h * 64;
    const bf16_t* vbase = vt + ((size_t)(b * HEADS + h) * 64) * SEQ;

    for (int kb = 0; kb < SEQ; kb += 64) {
        __syncthreads();   // all waves done reading previous K/V tiles
        if (wv < 2) {
            // K: instr i = wv*4+j -> plane p=i&1, rowgroup rg=i>>1 (16 keys)
            #pragma unroll
            for (int j = 0; j < 4; j++) {
                int i = wv * 4 + j, p = i & 1, rg = i >> 1;
                gload16(kbase + (size_t)(kb + rg * 16 + (lane >> 2)) * QKVN
                              + p * 32 + (lane & 3) * 8,
                        &Ks[p][rg * 16 * 32]);
            }
        } else {
            // V^T: instr i = (wv-2)*4+j -> dim-group dg (8 dims x 64 keys)
            #pragma unroll
            for (int j = 0; j < 4; j++) {
                int dg = (wv - 2) * 4 + j;
                gload16(vbase + (size_t)(dg * 8 + (lane >> 3)) * SEQ
                              + kb + (lane & 7) * 8,
                        &Vs[dg * 8 * 64]);
            }
        }
        __syncthreads();   // vmcnt drain: tiles landed

        // scores^T for 64 keys x 16 queries
        f32x4 s[4];
        #pragma unroll
        for (int tt = 0; tt < 4; tt++) {
            f32x4 z = {};
            z = __builtin_amdgcn_mfma_f32_16x16x32_bf16(
                    ld8(&Ks[0][(tt * 16 + l16) * 32 + quad * 8]), qf0, z, 0, 0, 0);
            z = __builtin_amdgcn_mfma_f32_16x16x32_bf16(
                    ld8(&Ks[1][(tt * 16 + l16) * 32 + quad * 8]), qf1, z, 0, 0, 0);
            s[tt] = z;   // s[tt][r]: key=kb+tt*16+quad*4+r, query=l16
        }
        float mx = -3e38f;
        #pragma unroll
        for (int tt = 0; tt < 4; tt++)
            #pragma unroll
            for (int r = 0; r < 4; r++) {
                s[tt][r] *= 0.125f;
                mx = fmaxf(mx, s[tt][r]);
            }
        mx = fmaxf(mx, __shfl_xor(mx, 16));
        mx = fmaxf(mx, __shfl_xor(mx, 32));
        float mn = fmaxf(m, mx);
        float alpha = exp2f((m - mn) * LOG2E);
        m = mn;
        float nb = mn * LOG2E;
        float rs = 0.0f;
        #pragma unroll
        for (int tt = 0; tt < 4; tt++) {
            bf16x4 pkt;
            #pragma unroll
            for (int r = 0; r < 4; r++) {
                float p = exp2f(fmaf(s[tt][r], LOG2E, -nb));
                rs += p;
                pkt[r] = (bf16_t)p;
            }
            *(bf16x4*)&P[l16 * 72 + tt * 16 + quad * 4] = pkt;
        }
        l = l * alpha + rs;   // quad-partial; reduced at end
        #pragma unroll
        for (int jt = 0; jt < 4; jt++) o[jt] *= alpha;
        asm volatile("s_waitcnt lgkmcnt(0)" ::: "memory");  // per-wave P visible
        bf16x8 pf0 = ld8(&P[l16 * 72 + quad * 8]);
        bf16x8 pf1 = ld8(&P[l16 * 72 + 32 + quad * 8]);
        #pragma unroll
        for (int jt = 0; jt < 4; jt++) {
            const bf16_t* vp = &Vs[(jt * 16 + l16) * 64];
            o[jt] = __builtin_amdgcn_mfma_f32_16x16x32_bf16(ld8(vp + quad * 8), pf0, o[jt], 0, 0, 0);
            o[jt] = __builtin_amdgcn_mfma_f32_16x16x32_bf16(ld8(vp + 32 + quad * 8), pf1, o[jt], 0, 0, 0);
        }
    }

    l += __shfl_xor(l, 16);
    l += __shfl_xor(l, 32);
    float inv = 1.0f / l;
    bf16_t* orow = out + (bS + qw0 + l16) * DIM + h * 64;
    #pragma unroll
    for (int jt = 0; jt < 4; jt++) {
        bf16x4 ov;
        #pragma unroll
        for (int r = 0; r < 4; r++) ov[r] = (bf16_t)(o[jt][r] * inv);
        *(bf16x4*)&orow[jt * 16 + quad * 4] = ov;
    }
}

extern "C" void kernel_launch(void* const* d_in, const int* in_sizes, int n_in,
                              void* d_out, int out_size, void* d_ws, size_t ws_size,
                              hipStream_t stream) {
    const float* x     = (const float*)d_in[0];
    const float* ln1_w = (const float*)d_in[1];
    const float* ln1_b = (const float*)d_in[2];
    const float* w_qkv = (const float*)d_in[3];
    const float* w_o   = (const float*)d_in[4];
    const float* b_o   = (const float*)d_in[5];
    const float* ln2_w = (const float*)d_in[6];
    const float* ln2_b = (const float*)d_in[7];
    const float* w1    = (const float*)d_in[8];
    const float* b1    = (const float*)d_in[9];
    const float* w2    = (const float*)d_in[10];
    const float* b2    = (const float*)d_in[11];
    float* out = (float*)d_out;

    char* ws = (char*)d_ws;
    size_t off = 0;
    auto alloc = [&](size_t elems) -> bf16_t* {
        bf16_t* p = (bf16_t*)(ws + off);
        off += (elems * 2 + 255) & ~(size_t)255;
        return p;
    };
    bf16_t* wqkv_t = alloc((size_t)DEPTH * DIM * QKVN);
    bf16_t* wo_t   = alloc((size_t)DEPTH * DIM * DIM);
    bf16_t* w1_t   = alloc((size_t)DEPTH * DIM * MLPD);
    bf16_t* w2_t   = alloc((size_t)DEPTH * MLPD * DIM);
    bf16_t* hbuf   = alloc((size_t)MTOT * DIM);
    bf16_t* qkvb   = alloc((size_t)MTOT * QKVN);
    bf16_t* vtb    = alloc((size_t)BATCH * HEADS * 64 * SEQ);
    bf16_t* aob    = alloc((size_t)MTOT * DIM);
    bf16_t* midb   = alloc((size_t)MTOT * MLPD);
    if (off > ws_size) return;

    tcvt_kernel<<<dim3(QKVN / 32, DIM / 32, DEPTH), 256, 0, stream>>>(w_qkv, wqkv_t, DIM, QKVN);
    tcvt_kernel<<<dim3(DIM / 32,  DIM / 32, DEPTH), 256, 0, stream>>>(w_o,   wo_t,   DIM, DIM);
    tcvt_kernel<<<dim3(MLPD / 32, DIM / 32, DEPTH), 256, 0, stream>>>(w1,    w1_t,   DIM, MLPD);
    tcvt_kernel<<<dim3(DIM / 32, MLPD / 32, DEPTH), 256, 0, stream>>>(w2,    w2_t,   MLPD, DIM);

    hipMemcpyAsync(out, x, (size_t)MTOT * DIM * 4, hipMemcpyDeviceToDevice, stream);

    for (int L = 0; L < DEPTH; L++) {
        ln_kernel<<<MTOT, 256, 0, stream>>>(out, ln1_w + L * DIM, ln1_b + L * DIM, hbuf);
        gemm_kernel<0><<<dim3(QKVN / 128, MTOT / 128, 1), 256, 0, stream>>>(
            hbuf, wqkv_t + (size_t)L * DIM * QKVN, nullptr, qkvb, nullptr, QKVN, DIM, DIM);
        vtrans_kernel<<<dim3(16, BATCH * HEADS), 256, 0, stream>>>(qkvb, vtb);
        attn_kernel<<<dim3(SEQ / 64, HEADS, BATCH), 256, 0, stream>>>(qkvb, vtb, aob);
        gemm_kernel<2><<<dim3(DIM / 128, MTOT / 128, 2), 256, 0, stream>>>(
            aob, wo_t + (size_t)L * DIM * DIM, b_o + L * DIM, nullptr, out, DIM, DIM, 384);
        ln_kernel<<<MTOT, 256, 0, stream>>>(out, ln2_w + L * DIM, ln2_b + L * DIM, hbuf);
        gemm_kernel<1><<<dim3(MLPD / 128, MTOT / 128, 1), 256, 0, stream>>>(
            hbuf, w1_t + (size_t)L * DIM * MLPD, b1 + L * MLPD, midb, nullptr, MLPD, DIM, DIM);
        gemm_kernel<2><<<dim3(DIM / 128, MTOT / 128, 4), 256, 0, stream>>>(
            midb, w2_t + (size_t)L * MLPD * DIM, b2 + L * DIM, nullptr, out, DIM, MLPD, 768);
    }
}

// Round 5
// 1345.749 us; speedup vs baseline: 1.6116x; 1.1186x over previous
//
#include <hip/hip_runtime.h>
#include <cmath>
#include <cstdint>

typedef __bf16 bf16_t;
typedef __bf16 bf16x8 __attribute__((ext_vector_type(8)));
typedef __bf16 bf16x4 __attribute__((ext_vector_type(4)));
typedef float  f32x4  __attribute__((ext_vector_type(4)));

#define DEPTH 6
#define DIM   768
#define HEADS 12
#define DH    64
#define MLPD  3072
#define SEQ   1024
#define BATCH 4
#define MTOT  (BATCH*SEQ)   /* 4096 rows */
#define QKVN  2304          /* 3*768 */

static __device__ __forceinline__ bf16x8 ld8(const bf16_t* p) {
    return *(const bf16x8*)p;
}

// async global->LDS, 16B per lane. LDS dest is wave-uniform base + lane*16.
typedef const __attribute__((address_space(1))) unsigned int gas_u32;
typedef __attribute__((address_space(3))) unsigned int las_u32;
static __device__ __forceinline__ void gload16(const bf16_t* g, bf16_t* l) {
    __builtin_amdgcn_global_load_lds((gas_u32*)g, (las_u32*)l, 16, 0, 0);
}

// ---------------- fp32 [K][N] -> bf16 [N][K] transposed weight ----------------
__global__ __launch_bounds__(256) void tcvt_kernel(const float* __restrict__ in,
                                                   bf16_t* __restrict__ out,
                                                   int K, int N) {
    __shared__ float ts[32][33];
    int n0 = blockIdx.x * 32, k0 = blockIdx.y * 32;
    size_t base = (size_t)blockIdx.z * K * N;
    int tx = threadIdx.x & 31, ty = threadIdx.x >> 5;   // 32 x 8
    #pragma unroll
    for (int r = 0; r < 32; r += 8)
        ts[ty + r][tx] = in[base + (size_t)(k0 + ty + r) * N + n0 + tx];
    __syncthreads();
    #pragma unroll
    for (int r = 0; r < 32; r += 8)
        out[base + (size_t)(n0 + ty + r) * K + k0 + tx] = (bf16_t)ts[tx][ty + r];
}

// ------- fused: x += bias + sum(partials); write x and LN(x) in one pass -----
// nslices==0: pure LN (x unchanged, not rewritten). writeLN==0: skip h write.
__global__ __launch_bounds__(256) void lnr_kernel(const float* __restrict__ xin,
                                                  float* __restrict__ xout,
                                                  const float* __restrict__ P,
                                                  int nslices,
                                                  const float* __restrict__ bias,
                                                  const float* __restrict__ w,
                                                  const float* __restrict__ b,
                                                  bf16_t* __restrict__ h,
                                                  int writeLN) {
    int row = blockIdx.x, t = threadIdx.x;
    size_t ro = (size_t)row * DIM;
    float v[3];
    #pragma unroll
    for (int e = 0; e < 3; e++) {
        int c = t + e * 256;
        float xv = xin[ro + c];
        if (nslices) {
            xv += bias[c];
            for (int s = 0; s < nslices; s++)
                xv += P[(size_t)s * MTOT * DIM + ro + c];
        }
        v[e] = xv;
    }
    if (nslices) {
        #pragma unroll
        for (int e = 0; e < 3; e++) xout[ro + t + e * 256] = v[e];
    }
    float s = v[0] + v[1] + v[2];
    float q = v[0] * v[0] + v[1] * v[1] + v[2] * v[2];
    #pragma unroll
    for (int off = 32; off > 0; off >>= 1) {
        s += __shfl_down(s, off);
        q += __shfl_down(q, off);
    }
    __shared__ float ss[4], sq[4], stat[2];
    if ((t & 63) == 0) { ss[t >> 6] = s; sq[t >> 6] = q; }
    __syncthreads();
    if (t == 0) {
        float S = ss[0] + ss[1] + ss[2] + ss[3];
        float Q = sq[0] + sq[1] + sq[2] + sq[3];
        float mean = S * (1.0f / DIM);
        float var  = Q * (1.0f / DIM) - mean * mean;
        stat[0] = mean;
        stat[1] = rsqrtf(var + 1e-5f);
    }
    __syncthreads();
    if (writeLN) {
        float mean = stat[0], rstd = stat[1];
        #pragma unroll
        for (int e = 0; e < 3; e++) {
            int c = t + e * 256;
            h[ro + c] = (bf16_t)((v[e] - mean) * rstd * w[c] + b[c]);
        }
    }
}

// ---------------- bf16 MFMA GEMM, BK=64 as two m97-style BK32 planes ---------
// A: [M][K] bf16, Bt: [N][K] bf16.
// EPI 0: Cb = A@B; V-tiles (n0>=1536) store transposed into Vt  (QKV)
// EPI 1: Cb = gelu(A@B+bias)                                    (MLP1)
// EPI 2: Cf[slice] = A@B  (plain fp32 partial store, split-K)   (proj/MLP2)
template <int EPI>
__global__ __launch_bounds__(256) void gemm_kernel(const bf16_t* __restrict__ A,
                                                   const bf16_t* __restrict__ Bt,
                                                   const float* __restrict__ bias,
                                                   bf16_t* __restrict__ Cb,
                                                   float* __restrict__ Cf,
                                                   bf16_t* __restrict__ Vt,
                                                   int N, int K, int klen) {
    __shared__ __align__(16) bf16_t As[2][128 * 32];
    __shared__ __align__(16) bf16_t Bs[2][128 * 32];
    int t = threadIdx.x;
    int m0 = blockIdx.y * 128, n0 = blockIdx.x * 128;
    int kz = blockIdx.z;
    int kbeg = kz * klen, kend = kbeg + klen;
    int lane = t & 63, l16 = lane & 15, quad = lane >> 4;
    int wv = t >> 6, wm = wv >> 1, wn = wv & 1;
    f32x4 acc[4][4] = {};

    int srow = wv * 16 + (lane >> 2);
    int skc  = (lane & 3) * 8;
    const bf16_t* ga = A  + (size_t)(m0 + srow) * K + skc;
    const bf16_t* gb = Bt + (size_t)(n0 + srow) * K + skc;
    size_t rh = (size_t)64 * K;

    for (int k0 = kbeg; k0 < kend; k0 += 64) {
        __syncthreads();
        #pragma unroll
        for (int p = 0; p < 2; p++) {
            gload16(ga + k0 + p * 32,      &As[p][(wv * 16) * 32]);
            gload16(ga + rh + k0 + p * 32, &As[p][(64 + wv * 16) * 32]);
            gload16(gb + k0 + p * 32,      &Bs[p][(wv * 16) * 32]);
            gload16(gb + rh + k0 + p * 32, &Bs[p][(64 + wv * 16) * 32]);
        }
        __syncthreads();
        #pragma unroll
        for (int p = 0; p < 2; p++) {
            bf16x8 af[4], bfr[4];
            #pragma unroll
            for (int i = 0; i < 4; i++)
                af[i] = ld8(&As[p][(wm * 64 + i * 16 + l16) * 32 + quad * 8]);
            #pragma unroll
            for (int j = 0; j < 4; j++)
                bfr[j] = ld8(&Bs[p][(wn * 64 + j * 16 + l16) * 32 + quad * 8]);
            #pragma unroll
            for (int i = 0; i < 4; i++)
                #pragma unroll
                for (int j = 0; j < 4; j++)
                    acc[i][j] = __builtin_amdgcn_mfma_f32_16x16x32_bf16(af[i], bfr[j], acc[i][j], 0, 0, 0);
        }
    }

    if constexpr (EPI == 0) {
        if (n0 >= 1536) {
            // V tile: store transposed into Vt[b][h][d][n], 8B per store
            int b = m0 >> 10;
            #pragma unroll
            for (int i = 0; i < 4; i++) {
                int n = (m0 & 1023) + wm * 64 + i * 16 + quad * 4;
                #pragma unroll
                for (int j = 0; j < 4; j++) {
                    int hc = n0 + wn * 64 + j * 16 + l16 - 1536;
                    int hh = hc >> 6, d = hc & 63;
                    bf16x4 ov;
                    #pragma unroll
                    for (int r = 0; r < 4; r++) ov[r] = (bf16_t)acc[i][j][r];
                    *(bf16x4*)&Vt[(((size_t)b * HEADS + hh) * 64 + d) * SEQ + n] = ov;
                }
            }
            return;
        }
    }
    #pragma unroll
    for (int i = 0; i < 4; i++) {
        int grow = m0 + wm * 64 + i * 16 + quad * 4;
        #pragma unroll
        for (int j = 0; j < 4; j++) {
            int gcol = n0 + wn * 64 + j * 16 + l16;
            float bv = 0.0f;
            if constexpr (EPI == 1) bv = bias[gcol];
            #pragma unroll
            for (int r = 0; r < 4; r++) {
                size_t idx = (size_t)(grow + r) * N + gcol;
                float v = acc[i][j][r];
                if constexpr (EPI == 0) {
                    Cb[idx] = (bf16_t)v;
                } else if constexpr (EPI == 1) {
                    v += bv;
                    v = 0.5f * v * (1.0f + erff(v * 0.70710678118654752f));
                    Cb[idx] = (bf16_t)v;
                } else {
                    Cf[(size_t)kz * MTOT * N + idx] = v;   // plain partial store
                }
            }
        }
    }
}

// ---------------- flash attention v3: LDS-staged K/V shared by 4 waves ------
__global__ __launch_bounds__(256) void attn_kernel(const bf16_t* __restrict__ qkv,
                                                   const bf16_t* __restrict__ vt,
                                                   bf16_t* __restrict__ out) {
    int qt = blockIdx.x, h = blockIdx.y, b = blockIdx.z;
    int t = threadIdx.x;
    int wv = t >> 6, lane = t & 63, l16 = lane & 15, quad = lane >> 4;
    const float LOG2E = 1.44269504f;
    int qw0 = qt * 64 + wv * 16;

    __shared__ __align__(16) bf16_t Ks[2][64 * 32];  // [plane][key][dim&31]
    __shared__ __align__(16) bf16_t Vs[64 * 64];     // [dim][key]
    __shared__ __align__(16) bf16_t Pa[4][16 * 72];  // per-wave P^T [query][key]
    bf16_t* P = Pa[wv];

    size_t bS = (size_t)b * SEQ;
    const bf16_t* qrow = qkv + (bS + qw0 + l16) * QKVN + h * 64;
    bf16x8 qf0 = ld8(qrow + quad * 8);
    bf16x8 qf1 = ld8(qrow + 32 + quad * 8);

    float m = -3e38f, l = 0.0f;
    f32x4 o[4] = {};

    const bf16_t* kbase = qkv + bS * QKVN + 768 + h * 64;
    const bf16_t* vbase = vt + ((size_t)(b * HEADS + h) * 64) * SEQ;

    for (int kb = 0; kb < SEQ; kb += 64) {
        __syncthreads();
        if (wv < 2) {
            #pragma unroll
            for (int j = 0; j < 4; j++) {
                int i = wv * 4 + j, p = i & 1, rg = i >> 1;
                gload16(kbase + (size_t)(kb + rg * 16 + (lane >> 2)) * QKVN
                              + p * 32 + (lane & 3) * 8,
                        &Ks[p][rg * 16 * 32]);
            }
        } else {
            #pragma unroll
            for (int j = 0; j < 4; j++) {
                int dg = (wv - 2) * 4 + j;
                gload16(vbase + (size_t)(dg * 8 + (lane >> 3)) * SEQ
                              + kb + (lane & 7) * 8,
                        &Vs[dg * 8 * 64]);
            }
        }
        __syncthreads();

        f32x4 s[4];
        #pragma unroll
        for (int tt = 0; tt < 4; tt++) {
            f32x4 z = {};
            z = __builtin_amdgcn_mfma_f32_16x16x32_bf16(
                    ld8(&Ks[0][(tt * 16 + l16) * 32 + quad * 8]), qf0, z, 0, 0, 0);
            z = __builtin_amdgcn_mfma_f32_16x16x32_bf16(
                    ld8(&Ks[1][(tt * 16 + l16) * 32 + quad * 8]), qf1, z, 0, 0, 0);
            s[tt] = z;
        }
        float mx = -3e38f;
        #pragma unroll
        for (int tt = 0; tt < 4; tt++)
            #pragma unroll
            for (int r = 0; r < 4; r++) {
                s[tt][r] *= 0.125f;
                mx = fmaxf(mx, s[tt][r]);
            }
        mx = fmaxf(mx, __shfl_xor(mx, 16));
        mx = fmaxf(mx, __shfl_xor(mx, 32));
        float mn = fmaxf(m, mx);
        float alpha = exp2f((m - mn) * LOG2E);
        m = mn;
        float nb = mn * LOG2E;
        float rs = 0.0f;
        #pragma unroll
        for (int tt = 0; tt < 4; tt++) {
            bf16x4 pkt;
            #pragma unroll
            for (int r = 0; r < 4; r++) {
                float p = exp2f(fmaf(s[tt][r], LOG2E, -nb));
                rs += p;
                pkt[r] = (bf16_t)p;
            }
            *(bf16x4*)&P[l16 * 72 + tt * 16 + quad * 4] = pkt;
        }
        l = l * alpha + rs;
        #pragma unroll
        for (int jt = 0; jt < 4; jt++) o[jt] *= alpha;
        asm volatile("s_waitcnt lgkmcnt(0)" ::: "memory");
        bf16x8 pf0 = ld8(&P[l16 * 72 + quad * 8]);
        bf16x8 pf1 = ld8(&P[l16 * 72 + 32 + quad * 8]);
        #pragma unroll
        for (int jt = 0; jt < 4; jt++) {
            const bf16_t* vp = &Vs[(jt * 16 + l16) * 64];
            o[jt] = __builtin_amdgcn_mfma_f32_16x16x32_bf16(ld8(vp + quad * 8), pf0, o[jt], 0, 0, 0);
            o[jt] = __builtin_amdgcn_mfma_f32_16x16x32_bf16(ld8(vp + 32 + quad * 8), pf1, o[jt], 0, 0, 0);
        }
    }

    l += __shfl_xor(l, 16);
    l += __shfl_xor(l, 32);
    float inv = 1.0f / l;
    bf16_t* orow = out + (bS + qw0 + l16) * DIM + h * 64;
    #pragma unroll
    for (int jt = 0; jt < 4; jt++) {
        bf16x4 ov;
        #pragma unroll
        for (int r = 0; r < 4; r++) ov[r] = (bf16_t)(o[jt][r] * inv);
        *(bf16x4*)&orow[jt * 16 + quad * 4] = ov;
    }
}

extern "C" void kernel_launch(void* const* d_in, const int* in_sizes, int n_in,
                              void* d_out, int out_size, void* d_ws, size_t ws_size,
                              hipStream_t stream) {
    const float* x     = (const float*)d_in[0];
    const float* ln1_w = (const float*)d_in[1];
    const float* ln1_b = (const float*)d_in[2];
    const float* w_qkv = (const float*)d_in[3];
    const float* w_o   = (const float*)d_in[4];
    const float* b_o   = (const float*)d_in[5];
    const float* ln2_w = (const float*)d_in[6];
    const float* ln2_b = (const float*)d_in[7];
    const float* w1    = (const float*)d_in[8];
    const float* b1    = (const float*)d_in[9];
    const float* w2    = (const float*)d_in[10];
    const float* b2    = (const float*)d_in[11];
    float* out = (float*)d_out;

    char* ws = (char*)d_ws;
    size_t off = 0;
    auto alloc = [&](size_t bytes) -> char* {
        char* p = ws + off;
        off += (bytes + 255) & ~(size_t)255;
        return p;
    };
    bf16_t* wqkv_t = (bf16_t*)alloc((size_t)DEPTH * DIM * QKVN * 2);
    bf16_t* wo_t   = (bf16_t*)alloc((size_t)DEPTH * DIM * DIM * 2);
    bf16_t* w1_t   = (bf16_t*)alloc((size_t)DEPTH * DIM * MLPD * 2);
    bf16_t* w2_t   = (bf16_t*)alloc((size_t)DEPTH * MLPD * DIM * 2);
    bf16_t* hbuf   = (bf16_t*)alloc((size_t)MTOT * DIM * 2);
    bf16_t* qkvb   = (bf16_t*)alloc((size_t)MTOT * QKVN * 2);   // also Pp slice 0/1
    bf16_t* vtb    = (bf16_t*)alloc((size_t)BATCH * HEADS * 64 * SEQ * 2);
    bf16_t* aob    = (bf16_t*)alloc((size_t)MTOT * DIM * 2);
    bf16_t* midb   = (bf16_t*)alloc((size_t)MTOT * MLPD * 2);
    float*  Pm     = (float*)alloc((size_t)4 * MTOT * DIM * 4); // MLP2 partials
    float*  Pp     = (float*)qkvb;  // proj partials: qkvb+vtb dead region, 24MB exact
    if (off > ws_size) return;

    tcvt_kernel<<<dim3(QKVN / 32, DIM / 32, DEPTH), 256, 0, stream>>>(w_qkv, wqkv_t, DIM, QKVN);
    tcvt_kernel<<<dim3(DIM / 32,  DIM / 32, DEPTH), 256, 0, stream>>>(w_o,   wo_t,   DIM, DIM);
    tcvt_kernel<<<dim3(MLPD / 32, DIM / 32, DEPTH), 256, 0, stream>>>(w1,    w1_t,   DIM, MLPD);
    tcvt_kernel<<<dim3(DIM / 32, MLPD / 32, DEPTH), 256, 0, stream>>>(w2,    w2_t,   MLPD, DIM);

    hipMemcpyAsync(out, x, (size_t)MTOT * DIM * 4, hipMemcpyDeviceToDevice, stream);

    // initial LN1 (layer 0)
    lnr_kernel<<<MTOT, 256, 0, stream>>>(out, out, nullptr, 0, nullptr,
                                         ln1_w, ln1_b, hbuf, 1);

    for (int L = 0; L < DEPTH; L++) {
        gemm_kernel<0><<<dim3(QKVN / 128, MTOT / 128, 1), 256, 0, stream>>>(
            hbuf, wqkv_t + (size_t)L * DIM * QKVN, nullptr, qkvb, nullptr, vtb,
            QKVN, DIM, DIM);
        attn_kernel<<<dim3(SEQ / 64, HEADS, BATCH), 256, 0, stream>>>(qkvb, vtb, aob);
        gemm_kernel<2><<<dim3(DIM / 128, MTOT / 128, 2), 256, 0, stream>>>(
            aob, wo_t + (size_t)L * DIM * DIM, nullptr, nullptr, Pp, nullptr,
            DIM, DIM, 384);
        lnr_kernel<<<MTOT, 256, 0, stream>>>(out, out, Pp, 2, b_o + L * DIM,
                                             ln2_w + L * DIM, ln2_b + L * DIM, hbuf, 1);
        gemm_kernel<1><<<dim3(MLPD / 128, MTOT / 128, 1), 256, 0, stream>>>(
            hbuf, w1_t + (size_t)L * DIM * MLPD, b1 + L * MLPD, midb, nullptr, nullptr,
            MLPD, DIM, DIM);
        gemm_kernel<2><<<dim3(DIM / 128, MTOT / 128, 4), 256, 0, stream>>>(
            midb, w2_t + (size_t)L * MLPD * DIM, nullptr, nullptr, Pm, nullptr,
            DIM, MLPD, 768);
        if (L < DEPTH - 1) {
            lnr_kernel<<<MTOT, 256, 0, stream>>>(out, out, Pm, 4, b2 + L * DIM,
                                                 ln1_w + (L + 1) * DIM,
                                                 ln1_b + (L + 1) * DIM, hbuf, 1);
        } else {
            lnr_kernel<<<MTOT, 256, 0, stream>>>(out, out, Pm, 4, b2 + L * DIM,
                                                 ln1_w, ln1_b, hbuf, 0);
        }
    }
}

// Round 6
// 1287.244 us; speedup vs baseline: 1.6849x; 1.0454x over previous
//
#include <hip/hip_runtime.h>
#include <cmath>
#include <cstdint>

typedef __bf16 bf16_t;
typedef __bf16 bf16x8 __attribute__((ext_vector_type(8)));
typedef __bf16 bf16x4 __attribute__((ext_vector_type(4)));
typedef float  f32x4  __attribute__((ext_vector_type(4)));

#define DEPTH 6
#define DIM   768
#define HEADS 12
#define DH    64
#define MLPD  3072
#define SEQ   1024
#define BATCH 4
#define MTOT  (BATCH*SEQ)   /* 4096 rows */
#define QKVN  2304          /* 3*768 */

static __device__ __forceinline__ bf16x8 ld8(const bf16_t* p) {
    return *(const bf16x8*)p;
}

// async global->LDS, 16B per lane. LDS dest is wave-uniform base + lane*16.
// We permute *source* addresses per lane to build XOR-swizzled LDS layouts.
typedef const __attribute__((address_space(1))) unsigned int gas_u32;
typedef __attribute__((address_space(3))) unsigned int las_u32;
static __device__ __forceinline__ void gload16(const bf16_t* g, bf16_t* l) {
    __builtin_amdgcn_global_load_lds((gas_u32*)g, (las_u32*)l, 16, 0, 0);
}

// ---------------- fp32 [K][N] -> bf16 [N][K] transposed weight ----------------
__global__ __launch_bounds__(256) void tcvt_kernel(const float* __restrict__ in,
                                                   bf16_t* __restrict__ out,
                                                   int K, int N) {
    __shared__ float ts[32][33];
    int n0 = blockIdx.x * 32, k0 = blockIdx.y * 32;
    size_t base = (size_t)blockIdx.z * K * N;
    int tx = threadIdx.x & 31, ty = threadIdx.x >> 5;   // 32 x 8
    #pragma unroll
    for (int r = 0; r < 32; r += 8)
        ts[ty + r][tx] = in[base + (size_t)(k0 + ty + r) * N + n0 + tx];
    __syncthreads();
    #pragma unroll
    for (int r = 0; r < 32; r += 8)
        out[base + (size_t)(n0 + ty + r) * K + k0 + tx] = (bf16_t)ts[tx][ty + r];
}

// ------- fused: x += bias + sum(partials); write x and LN(x), float4 lanes ---
// 192 threads, one float4 column-group each. nslices==0: pure LN.
__global__ __launch_bounds__(192) void lnr_kernel(const float* __restrict__ xin,
                                                  float* __restrict__ xout,
                                                  const float* __restrict__ P,
                                                  int nslices,
                                                  const float* __restrict__ bias,
                                                  const float* __restrict__ w,
                                                  const float* __restrict__ b,
                                                  bf16_t* __restrict__ h,
                                                  int writeLN) {
    int row = blockIdx.x, t = threadIdx.x;
    size_t r4 = (size_t)row * 192 + t;
    float4 v = ((const float4*)xin)[r4];
    if (nslices) {
        float4 bi = ((const float4*)bias)[t];
        v.x += bi.x; v.y += bi.y; v.z += bi.z; v.w += bi.w;
        for (int s = 0; s < nslices; s++) {
            float4 pv = ((const float4*)P)[(size_t)s * MTOT * 192 + r4];
            v.x += pv.x; v.y += pv.y; v.z += pv.z; v.w += pv.w;
        }
        ((float4*)xout)[r4] = v;
    }
    float s = v.x + v.y + v.z + v.w;
    float q = v.x * v.x + v.y * v.y + v.z * v.z + v.w * v.w;
    #pragma unroll
    for (int off = 32; off > 0; off >>= 1) {
        s += __shfl_down(s, off);
        q += __shfl_down(q, off);
    }
    __shared__ float ss[3], sq[3], stat[2];
    if ((t & 63) == 0) { ss[t >> 6] = s; sq[t >> 6] = q; }
    __syncthreads();
    if (t == 0) {
        float S = ss[0] + ss[1] + ss[2];
        float Q = sq[0] + sq[1] + sq[2];
        float mean = S * (1.0f / DIM);
        float var  = Q * (1.0f / DIM) - mean * mean;
        stat[0] = mean;
        stat[1] = rsqrtf(var + 1e-5f);
    }
    __syncthreads();
    if (writeLN) {
        float mean = stat[0], rstd = stat[1];
        float4 wv4 = ((const float4*)w)[t];
        float4 bv4 = ((const float4*)b)[t];
        bf16x4 o;
        o[0] = (bf16_t)((v.x - mean) * rstd * wv4.x + bv4.x);
        o[1] = (bf16_t)((v.y - mean) * rstd * wv4.y + bv4.y);
        o[2] = (bf16_t)((v.z - mean) * rstd * wv4.z + bv4.z);
        o[3] = (bf16_t)((v.w - mean) * rstd * wv4.w + bv4.w);
        *(bf16x4*)&h[(size_t)row * DIM + t * 4] = o;
    }
}

// ---------------- bf16 MFMA GEMM: swizzled LDS + one-barrier prefetch --------
// A: [M][K] bf16, Bt: [N][K] bf16. 128x128 tile, BK=32, double-buffered LDS.
// LDS layout: row-major [128][32] with chunk position = chunk ^ ((row>>1)&3)
// (2-way bank aliasing only). Per iter: barrier -> prefetch next tile (async
// DMA, overlaps compute) -> compute current.
// EPI 0: Cb = A@B; V-tiles (n0>=1536) store transposed into Vt  (QKV)
// EPI 1: Cb = gelu(A@B+bias)                                    (MLP1)
// EPI 2: Cf[slice] = A@B  (plain fp32 partial store, split-K)   (proj/MLP2)
template <int EPI>
__global__ __launch_bounds__(256) void gemm_kernel(const bf16_t* __restrict__ A,
                                                   const bf16_t* __restrict__ Bt,
                                                   const float* __restrict__ bias,
                                                   bf16_t* __restrict__ Cb,
                                                   float* __restrict__ Cf,
                                                   bf16_t* __restrict__ Vt,
                                                   int N, int K, int klen) {
    __shared__ __align__(16) bf16_t As[2][128 * 32];
    __shared__ __align__(16) bf16_t Bs[2][128 * 32];
    int t = threadIdx.x;
    int m0 = blockIdx.y * 128, n0 = blockIdx.x * 128;
    int kz = blockIdx.z;
    int kbeg = kz * klen;
    int lane = t & 63, l16 = lane & 15, quad = lane >> 4;
    int wv = t >> 6, wm = wv >> 1, wn = wv & 1;
    f32x4 acc[4][4] = {};

    // staging: wave wv covers rows wv*32..wv*32+31 (two 1KB instrs per tensor).
    // lane ln -> row ln>>2 in group, LDS chunk-pos ln&3 holding global chunk
    // (ln&3)^((ln>>3)&3)  [= pos ^ ((row>>1)&3)].
    int sr = lane >> 2;
    int sc = ((lane & 3) ^ ((lane >> 3) & 3)) * 8;
    const bf16_t* gA0 = A  + (size_t)(m0 + wv * 32 + sr) * K + sc;
    const bf16_t* gA1 = gA0 + (size_t)16 * K;
    const bf16_t* gB0 = Bt + (size_t)(n0 + wv * 32 + sr) * K + sc;
    const bf16_t* gB1 = gB0 + (size_t)16 * K;
    bf16_t* lA0 = &As[0][(wv * 32) * 32];
    bf16_t* lA1 = &As[0][(wv * 32 + 16) * 32];
    bf16_t* lB0 = &Bs[0][(wv * 32) * 32];
    bf16_t* lB1 = &Bs[0][(wv * 32 + 16) * 32];
    const int bufoff = 128 * 32;

    auto stage = [&](int buf, int k0) {
        gload16(gA0 + k0, lA0 + buf * bufoff);
        gload16(gA1 + k0, lA1 + buf * bufoff);
        gload16(gB0 + k0, lB0 + buf * bufoff);
        gload16(gB1 + k0, lB1 + buf * bufoff);
    };

    int nIt = klen >> 5;
    stage(0, kbeg);
    int posA = (quad ^ ((l16 >> 1) & 3)) * 8;   // swizzled frag chunk (2-way)

    for (int it = 0; it < nIt; it++) {
        __syncthreads();   // drains all waves' DMA -> buf[it&1] ready; other buf free
        if (it + 1 < nIt) stage((it + 1) & 1, kbeg + (it + 1) * 32);
        const bf16_t* as = As[it & 1];
        const bf16_t* bs = Bs[it & 1];
        bf16x8 af[4], bfr[4];
        #pragma unroll
        for (int i = 0; i < 4; i++)
            af[i] = ld8(&as[(wm * 64 + i * 16 + l16) * 32 + posA]);
        #pragma unroll
        for (int j = 0; j < 4; j++)
            bfr[j] = ld8(&bs[(wn * 64 + j * 16 + l16) * 32 + posA]);
        #pragma unroll
        for (int i = 0; i < 4; i++)
            #pragma unroll
            for (int j = 0; j < 4; j++)
                acc[i][j] = __builtin_amdgcn_mfma_f32_16x16x32_bf16(af[i], bfr[j], acc[i][j], 0, 0, 0);
    }

    if constexpr (EPI == 0) {
        if (n0 >= 1536) {
            // V tile: store transposed into Vt[b][h][d][n], 8B per store
            int b = m0 >> 10;
            #pragma unroll
            for (int i = 0; i < 4; i++) {
                int n = (m0 & 1023) + wm * 64 + i * 16 + quad * 4;
                #pragma unroll
                for (int j = 0; j < 4; j++) {
                    int hc = n0 + wn * 64 + j * 16 + l16 - 1536;
                    int hh = hc >> 6, d = hc & 63;
                    bf16x4 ov;
                    #pragma unroll
                    for (int r = 0; r < 4; r++) ov[r] = (bf16_t)acc[i][j][r];
                    *(bf16x4*)&Vt[(((size_t)b * HEADS + hh) * 64 + d) * SEQ + n] = ov;
                }
            }
            return;
        }
    }
    #pragma unroll
    for (int i = 0; i < 4; i++) {
        int grow = m0 + wm * 64 + i * 16 + quad * 4;
        #pragma unroll
        for (int j = 0; j < 4; j++) {
            int gcol = n0 + wn * 64 + j * 16 + l16;
            float bv = 0.0f;
            if constexpr (EPI == 1) bv = bias[gcol];
            #pragma unroll
            for (int r = 0; r < 4; r++) {
                size_t idx = (size_t)(grow + r) * N + gcol;
                float v = acc[i][j][r];
                if constexpr (EPI == 0) {
                    Cb[idx] = (bf16_t)v;
                } else if constexpr (EPI == 1) {
                    v += bv;
                    v = 0.5f * v * (1.0f + erff(v * 0.70710678118654752f));
                    Cb[idx] = (bf16_t)v;
                } else {
                    Cf[(size_t)kz * MTOT * N + idx] = v;   // plain partial store
                }
            }
        }
    }
}

// ---------------- flash attention v4: swizzled dbuf K/V + prefetch ----------
// Block = (b, h, 64 queries); wave wv owns 16 queries over full key range.
// K/V tiles [64][64] XOR-swizzled (pos = chunk^(row&7), 2-way banks),
// double-buffered; per iter: barrier -> prefetch next -> compute.
__global__ __launch_bounds__(256) void attn_kernel(const bf16_t* __restrict__ qkv,
                                                   const bf16_t* __restrict__ vt,
                                                   bf16_t* __restrict__ out) {
    int qt = blockIdx.x, h = blockIdx.y, b = blockIdx.z;
    int t = threadIdx.x;
    int wv = t >> 6, lane = t & 63, l16 = lane & 15, quad = lane >> 4;
    const float LOG2E = 1.44269504f;
    int qw0 = qt * 64 + wv * 16;

    __shared__ __align__(16) bf16_t Ks[2][64 * 64];
    __shared__ __align__(16) bf16_t Vs[2][64 * 64];
    __shared__ __align__(16) bf16_t Pa[4][16 * 72];
    bf16_t* P = Pa[wv];

    size_t bS = (size_t)b * SEQ;
    const bf16_t* qrow = qkv + (bS + qw0 + l16) * QKVN + h * 64;
    bf16x8 qf0 = ld8(qrow + quad * 8);
    bf16x8 qf1 = ld8(qrow + 32 + quad * 8);

    float m = -3e38f, l = 0.0f;
    f32x4 o[4] = {};

    const bf16_t* kbase = qkv + bS * QKVN + 768 + h * 64;
    const bf16_t* vbase = vt + ((size_t)(b * HEADS + h) * 64) * SEQ;

    // staging: wave wv handles K instrs {wv*2, wv*2+1} and V instrs {wv*2, wv*2+1}.
    // lane ln -> row ln>>3 in 8-row group, pos ln&7 holds chunk (ln&7)^(ln>>3).
    int ar = lane >> 3;
    int ac = ((lane & 7) ^ ar) * 8;
    int i0 = wv * 2, i1 = wv * 2 + 1;
    const bf16_t* gK0 = kbase + (size_t)(i0 * 8 + ar) * QKVN + ac;
    const bf16_t* gK1 = kbase + (size_t)(i1 * 8 + ar) * QKVN + ac;
    const bf16_t* gV0 = vbase + (size_t)(i0 * 8 + ar) * SEQ + ac;
    const bf16_t* gV1 = vbase + (size_t)(i1 * 8 + ar) * SEQ + ac;

    auto stage = [&](int buf, int kb) {
        gload16(gK0 + (size_t)kb * QKVN, &Ks[buf][i0 * 8 * 64]);
        gload16(gK1 + (size_t)kb * QKVN, &Ks[buf][i1 * 8 * 64]);
        gload16(gV0 + kb, &Vs[buf][i0 * 8 * 64]);
        gload16(gV1 + kb, &Vs[buf][i1 * 8 * 64]);
    };

    stage(0, 0);
    int p0 = (quad ^ (l16 & 7)) * 8;         // chunks 0..3 (swizzled)
    int p1 = ((quad + 4) ^ (l16 & 7)) * 8;   // chunks 4..7 (swizzled)

    for (int it = 0; it < SEQ / 64; it++) {
        __syncthreads();
        if (it + 1 < SEQ / 64) stage((it + 1) & 1, (it + 1) * 64);
        const bf16_t* ks = Ks[it & 1];
        const bf16_t* vs = Vs[it & 1];

        f32x4 s[4];
        #pragma unroll
        for (int tt = 0; tt < 4; tt++) {
            const bf16_t* kr = &ks[(tt * 16 + l16) * 64];
            f32x4 z = {};
            z = __builtin_amdgcn_mfma_f32_16x16x32_bf16(ld8(kr + p0), qf0, z, 0, 0, 0);
            z = __builtin_amdgcn_mfma_f32_16x16x32_bf16(ld8(kr + p1), qf1, z, 0, 0, 0);
            s[tt] = z;   // s[tt][r]: key=it*64+tt*16+quad*4+r, query=l16
        }
        float mx = -3e38f;
        #pragma unroll
        for (int tt = 0; tt < 4; tt++)
            #pragma unroll
            for (int r = 0; r < 4; r++) {
                s[tt][r] *= 0.125f;
                mx = fmaxf(mx, s[tt][r]);
            }
        mx = fmaxf(mx, __shfl_xor(mx, 16));
        mx = fmaxf(mx, __shfl_xor(mx, 32));
        float mn = fmaxf(m, mx);
        float alpha = exp2f((m - mn) * LOG2E);
        m = mn;
        float nb = mn * LOG2E;
        float rs = 0.0f;
        #pragma unroll
        for (int tt = 0; tt < 4; tt++) {
            bf16x4 pkt;
            #pragma unroll
            for (int r = 0; r < 4; r++) {
                float p = exp2f(fmaf(s[tt][r], LOG2E, -nb));
                rs += p;
                pkt[r] = (bf16_t)p;
            }
            *(bf16x4*)&P[l16 * 72 + tt * 16 + quad * 4] = pkt;
        }
        l = l * alpha + rs;   // quad-partial; reduced at end
        #pragma unroll
        for (int jt = 0; jt < 4; jt++) o[jt] *= alpha;
        asm volatile("s_waitcnt lgkmcnt(0)" ::: "memory");  // per-wave P visible
        bf16x8 pf0 = ld8(&P[l16 * 72 + quad * 8]);
        bf16x8 pf1 = ld8(&P[l16 * 72 + 32 + quad * 8]);
        #pragma unroll
        for (int jt = 0; jt < 4; jt++) {
            const bf16_t* vr = &vs[(jt * 16 + l16) * 64];
            o[jt] = __builtin_amdgcn_mfma_f32_16x16x32_bf16(ld8(vr + p0), pf0, o[jt], 0, 0, 0);
            o[jt] = __builtin_amdgcn_mfma_f32_16x16x32_bf16(ld8(vr + p1), pf1, o[jt], 0, 0, 0);
        }
    }

    l += __shfl_xor(l, 16);
    l += __shfl_xor(l, 32);
    float inv = 1.0f / l;
    bf16_t* orow = out + (bS + qw0 + l16) * DIM + h * 64;
    #pragma unroll
    for (int jt = 0; jt < 4; jt++) {
        bf16x4 ov;
        #pragma unroll
        for (int r = 0; r < 4; r++) ov[r] = (bf16_t)(o[jt][r] * inv);
        *(bf16x4*)&orow[jt * 16 + quad * 4] = ov;
    }
}

extern "C" void kernel_launch(void* const* d_in, const int* in_sizes, int n_in,
                              void* d_out, int out_size, void* d_ws, size_t ws_size,
                              hipStream_t stream) {
    const float* x     = (const float*)d_in[0];
    const float* ln1_w = (const float*)d_in[1];
    const float* ln1_b = (const float*)d_in[2];
    const float* w_qkv = (const float*)d_in[3];
    const float* w_o   = (const float*)d_in[4];
    const float* b_o   = (const float*)d_in[5];
    const float* ln2_w = (const float*)d_in[6];
    const float* ln2_b = (const float*)d_in[7];
    const float* w1    = (const float*)d_in[8];
    const float* b1    = (const float*)d_in[9];
    const float* w2    = (const float*)d_in[10];
    const float* b2    = (const float*)d_in[11];
    float* out = (float*)d_out;

    char* ws = (char*)d_ws;
    size_t off = 0;
    auto alloc = [&](size_t bytes) -> char* {
        char* p = ws + off;
        off += (bytes + 255) & ~(size_t)255;
        return p;
    };
    bf16_t* wqkv_t = (bf16_t*)alloc((size_t)DEPTH * DIM * QKVN * 2);
    bf16_t* wo_t   = (bf16_t*)alloc((size_t)DEPTH * DIM * DIM * 2);
    bf16_t* w1_t   = (bf16_t*)alloc((size_t)DEPTH * DIM * MLPD * 2);
    bf16_t* w2_t   = (bf16_t*)alloc((size_t)DEPTH * MLPD * DIM * 2);
    bf16_t* hbuf   = (bf16_t*)alloc((size_t)MTOT * DIM * 2);
    bf16_t* qkvb   = (bf16_t*)alloc((size_t)MTOT * QKVN * 2);   // also Pp slice 0/1
    bf16_t* vtb    = (bf16_t*)alloc((size_t)BATCH * HEADS * 64 * SEQ * 2);
    bf16_t* aob    = (bf16_t*)alloc((size_t)MTOT * DIM * 2);
    bf16_t* midb   = (bf16_t*)alloc((size_t)MTOT * MLPD * 2);
    float*  Pm     = (float*)alloc((size_t)4 * MTOT * DIM * 4); // MLP2 partials
    float*  Pp     = (float*)qkvb;  // proj partials alias dead qkvb+vtb region
    if (off > ws_size) return;

    tcvt_kernel<<<dim3(QKVN / 32, DIM / 32, DEPTH), 256, 0, stream>>>(w_qkv, wqkv_t, DIM, QKVN);
    tcvt_kernel<<<dim3(DIM / 32,  DIM / 32, DEPTH), 256, 0, stream>>>(w_o,   wo_t,   DIM, DIM);
    tcvt_kernel<<<dim3(MLPD / 32, DIM / 32, DEPTH), 256, 0, stream>>>(w1,    w1_t,   DIM, MLPD);
    tcvt_kernel<<<dim3(DIM / 32, MLPD / 32, DEPTH), 256, 0, stream>>>(w2,    w2_t,   MLPD, DIM);

    hipMemcpyAsync(out, x, (size_t)MTOT * DIM * 4, hipMemcpyDeviceToDevice, stream);

    // initial LN1 (layer 0)
    lnr_kernel<<<MTOT, 192, 0, stream>>>(out, out, nullptr, 0, nullptr,
                                         ln1_w, ln1_b, hbuf, 1);

    for (int L = 0; L < DEPTH; L++) {
        gemm_kernel<0><<<dim3(QKVN / 128, MTOT / 128, 1), 256, 0, stream>>>(
            hbuf, wqkv_t + (size_t)L * DIM * QKVN, nullptr, qkvb, nullptr, vtb,
            QKVN, DIM, DIM);
        attn_kernel<<<dim3(SEQ / 64, HEADS, BATCH), 256, 0, stream>>>(qkvb, vtb, aob);
        gemm_kernel<2><<<dim3(DIM / 128, MTOT / 128, 2), 256, 0, stream>>>(
            aob, wo_t + (size_t)L * DIM * DIM, nullptr, nullptr, Pp, nullptr,
            DIM, DIM, 384);
        lnr_kernel<<<MTOT, 192, 0, stream>>>(out, out, Pp, 2, b_o + L * DIM,
                                             ln2_w + L * DIM, ln2_b + L * DIM, hbuf, 1);
        gemm_kernel<1><<<dim3(MLPD / 128, MTOT / 128, 1), 256, 0, stream>>>(
            hbuf, w1_t + (size_t)L * DIM * MLPD, b1 + L * MLPD, midb, nullptr, nullptr,
            MLPD, DIM, DIM);
        gemm_kernel<2><<<dim3(DIM / 128, MTOT / 128, 4), 256, 0, stream>>>(
            midb, w2_t + (size_t)L * MLPD * DIM, nullptr, nullptr, Pm, nullptr,
            DIM, MLPD, 768);
        if (L < DEPTH - 1) {
            lnr_kernel<<<MTOT, 192, 0, stream>>>(out, out, Pm, 4, b2 + L * DIM,
                                                 ln1_w + (L + 1) * DIM,
                                                 ln1_b + (L + 1) * DIM, hbuf, 1);
        } else {
            lnr_kernel<<<MTOT, 192, 0, stream>>>(out, out, Pm, 4, b2 + L * DIM,
                                                 ln1_w, ln1_b, hbuf, 0);
        }
    }
}